// Round 12
// baseline (2071.697 us; speedup 1.0000x reference)
//
#include <hip/hip_runtime.h>

// DRL4SSP pointer-network decoder, MI355X (gfx950).
// 64 batches -> 64 blocks x 1024 threads (16 waves, 4 waves/SIMD), 127
// sequential steps, 8 lgkmcnt-only barriers/step. STATIC 159 KB LDS so the
// compiler KNOWS 1 block/CU -> register budget 128 VGPR at 4 waves/SIMD ->
// the ~110-reg working set fits with zero spill (round-11's design, realized).

namespace {

constexpr int kB = 64, kSS = 8, kDS = 4, kH = 128, kS = 128, kT = 127, kG3 = 384;

// workspace layout (float offsets)
constexpr size_t OFF_BASE1 = 0;
constexpr size_t OFF_BASE2 = OFF_BASE1 + (size_t)kB * kH * kS;
constexpr size_t OFF_SHG   = OFF_BASE2 + (size_t)kB * kH * kS;   // static_h [b][h][s]
constexpr size_t OFF_DHG   = OFF_SHG   + (size_t)kB * kH * kS;
constexpr size_t OFF_WCT   = OFF_DHG   + (size_t)kB * kH * kS;   // WcombT [8][384]
constexpr size_t OFF_BCOMB = OFF_WCT   + (size_t)kSS * kG3;

// static-LDS layout (float offsets)
constexpr int L_BASE1 = 0;        // 16384
constexpr int L_BASE2 = 16384;    // 16384
constexpr int L_BC    = 32768;    // 384
constexpr int L_BH    = 33152;    // 384
constexpr int L_STAT  = 33536;    // 1024
constexpr int L_PG    = 34560;    // 3072  [8 seg][3 gate][128]
constexpr int L_PU    = 37632;    // 1024  [8 seg][128]
constexpr int L_PA    = 38656;    // 1024
constexpr int L_MASK  = 39680;    // 128
constexpr int L_DEC   = 39808;    // 8
constexpr int L_WSUM  = 39816;    // 8
constexpr int L_RINV  = 39824;    // 1
constexpr int LDS_FLOATS = 39828; // 159,312 B <= 163,840

__device__ __forceinline__ float rlane(float v, int l) {
  return __uint_as_float(__builtin_amdgcn_readlane(__float_as_uint(v), (unsigned)l));
}

__device__ __forceinline__ float tanh_fast(float x) {
  // identical to the round-1..11 (passing) formula — trajectory-sensitive
  x = fminf(15.f, fmaxf(-15.f, x));
  float e = __expf(-2.f * x);
  return (1.f - e) * __builtin_amdgcn_rcpf(1.f + e);
}

// LDS-only barrier: drain DS ops, do NOT drain vmcnt — in-flight global
// (read-only weight prefetch) loads ride across.
__device__ __forceinline__ void lds_barrier() {
  asm volatile("s_waitcnt lgkmcnt(0)" ::: "memory");
  __builtin_amdgcn_s_barrier();
}

// ---------------- precompute kernels ----------------

__global__ void prep_w(const float* __restrict__ W_ih, const float* __restrict__ W_dec,
                       const float* __restrict__ b_ih, const float* __restrict__ b_dec,
                       float* __restrict__ ws) {
  const int tid = threadIdx.x;
  float* WcT   = ws + OFF_WCT;    // [i][j] = sum_k W_ih[j,k] W_dec[k,i]
  float* bcomb = ws + OFF_BCOMB;
  for (int idx = tid; idx < kSS * kG3; idx += 256) {
    int i = idx / kG3, j = idx % kG3;
    float acc = 0.f;
    for (int k = 0; k < kH; ++k) acc = fmaf(W_ih[j * kH + k], W_dec[k * kSS + i], acc);
    WcT[idx] = acc;
  }
  for (int j = tid; j < kG3; j += 256) {
    float acc = b_ih[j];
    for (int k = 0; k < kH; ++k) acc = fmaf(W_ih[j * kH + k], b_dec[k], acc);
    bcomb[j] = acc;
  }
}

__global__ void prep_sh(const float* __restrict__ stat_g, const float* __restrict__ dyn_g,
                        const float* __restrict__ W_s, const float* __restrict__ b_s,
                        const float* __restrict__ W_d, const float* __restrict__ b_d,
                        float* __restrict__ ws) {
  const int b = blockIdx.x, tid = threadIdx.x;
  float* sh_g = ws + OFF_SHG;
  float* dh_g = ws + OFF_DHG;
  const float* sb = stat_g + (size_t)b * kSS * kS;
  const float* db = dyn_g + (size_t)b * kDS * kS;
  for (int idx = tid; idx < kH * kS; idx += 256) {
    int k = idx >> 7, s = idx & 127;
    float acc = b_s[k];
#pragma unroll
    for (int i = 0; i < kSS; ++i) acc = fmaf(W_s[k * kSS + i], sb[i * kS + s], acc);
    sh_g[(size_t)b * kH * kS + idx] = acc;
    float accd = b_d[k];
#pragma unroll
    for (int i = 0; i < kDS; ++i) accd = fmaf(W_d[k * kDS + i], db[i * kS + s], accd);
    dh_g[(size_t)b * kH * kS + idx] = accd;
  }
}

__global__ void prep_base(const float* __restrict__ ww1, const float* __restrict__ ww2,
                          float* __restrict__ ws) {
  const int b = blockIdx.x, which = blockIdx.y, tid = threadIdx.x;
  const float* sh_g = ws + OFF_SHG + (size_t)b * kH * kS;
  const float* dh_g = ws + OFF_DHG + (size_t)b * kH * kS;
  const float* ww = which ? ww2 : ww1;
  const int dh_off = which ? 2 * kH : kH;
  float* dst = ws + (which ? OFF_BASE2 : OFF_BASE1) + (size_t)b * kH * kS;
  for (int idx = tid; idx < kH * kS / 4; idx += 256) {
    int h = idx >> 5, sq = idx & 31;
    const float* wrow = ww + h * kG3;
    float4 acc = make_float4(0.f, 0.f, 0.f, 0.f);
#pragma unroll 8
    for (int k = 0; k < kH; ++k) {
      float w = wrow[k];
      float4 v = *reinterpret_cast<const float4*>(sh_g + k * kS + sq * 4);
      acc.x = fmaf(w, v.x, acc.x); acc.y = fmaf(w, v.y, acc.y);
      acc.z = fmaf(w, v.z, acc.z); acc.w = fmaf(w, v.w, acc.w);
    }
#pragma unroll 8
    for (int k = 0; k < kH; ++k) {
      float w = wrow[dh_off + k];
      float4 v = *reinterpret_cast<const float4*>(dh_g + k * kS + sq * 4);
      acc.x = fmaf(w, v.x, acc.x); acc.y = fmaf(w, v.y, acc.y);
      acc.z = fmaf(w, v.z, acc.z); acc.w = fmaf(w, v.w, acc.w);
    }
    *reinterpret_cast<float4*>(dst + h * kS + sq * 4) = acc;
  }
}

// ---------------- main sequential kernel ----------------

__global__ __launch_bounds__(1024)
__attribute__((amdgpu_waves_per_eu(4, 4)))
void ptrnet_main(
    const float* __restrict__ stat_g, const float* __restrict__ dyn_g,
    const float* __restrict__ vv1_g, const float* __restrict__ vv2_g,
    const float* __restrict__ bhh_g, const float* __restrict__ Whh_g,
    const float* __restrict__ ww1_g, const float* __restrict__ ww2_g,
    const float* __restrict__ ws, float* __restrict__ out) {
  __shared__ float sm[LDS_FLOATS];   // STATIC: compiler sees 159 KB -> 1 block/CU
  const int b = blockIdx.x;
  const int tid = threadIdx.x;
  const int hh = tid & 127;            // output/s column
  const int seg = tid >> 7;            // 0..7: 16-row chunk
  const int lane = tid & 63;
  const int li = seg * 16 + (hh & 15); // owned 128-index; repeats every 16 lanes

  float* base1_l = sm + L_BASE1;
  float* base2_l = sm + L_BASE2;
  float* bc_l    = sm + L_BC;
  float* bh_l    = sm + L_BH;
  float* stat_l  = sm + L_STAT;
  float* pg_l    = sm + L_PG;
  float* pu_l    = sm + L_PU;
  float* pa_l    = sm + L_PA;
  float* mask_l  = sm + L_MASK;
  float* dec_l   = sm + L_DEC;
  float* wsum_l  = sm + L_WSUM;
  float* rinv_l  = sm + L_RINV;

  // ---- LDS init (one-time) ----
  {
    const float4* b1g = reinterpret_cast<const float4*>(ws + OFF_BASE1 + (size_t)b * kH * kS);
    const float4* b2g = reinterpret_cast<const float4*>(ws + OFF_BASE2 + (size_t)b * kH * kS);
    float4* b1l = reinterpret_cast<float4*>(base1_l);
    float4* b2l = reinterpret_cast<float4*>(base2_l);
    for (int i = tid; i < kH * kS / 4; i += 1024) { b1l[i] = b1g[i]; b2l[i] = b2g[i]; }
    if (tid < kG3) { bc_l[tid] = ws[OFF_BCOMB + tid]; bh_l[tid] = bhh_g[tid]; }
    for (int i = tid; i < kSS * kS; i += 1024) stat_l[i] = stat_g[(size_t)b * kSS * kS + i];
    if (tid < kS)
      mask_l[tid] = (tid == 0 || dyn_g[(size_t)b * kDS * kS + tid] != 0.f) ? 0.f : 1.f;
    if (tid < kSS) dec_l[tid] = 0.f;
  }

  // ---- step-invariant register caches ----
  float wcr0[8], wcr1[8], wcr2[8];   // WcombT columns for own li
#pragma unroll
  for (int i = 0; i < 8; ++i) {
    wcr0[i] = ws[OFF_WCT + (size_t)i * kG3 + li];
    wcr1[i] = ws[OFF_WCT + (size_t)i * kG3 + kH + li];
    wcr2[i] = ws[OFF_WCT + (size_t)i * kG3 + 2 * kH + li];
  }
  float v_vv1 = vv1_g[li], v_vv2 = vv2_g[li];
  float h_prev = 0.f;

  // per-thread contiguous weight rows (16 floats = 4 dwordx4 each)
  const float* whpr = Whh_g + (size_t)(0 * kH + hh) * kH + seg * 16;  // gate r
  const float* whpz = whpr + (size_t)kH * kH;                         // gate z
  const float* whpn = whpz + (size_t)kH * kH;                         // gate n
  const float* w1row = ww1_g + (size_t)hh * kG3 + 2 * kH + seg * 16;  // w1h[hh][rows]
  const float* w2row = ww2_g + (size_t)hh * kG3 + kH + seg * 16;      // w2d[hh][rows]
  const float* shrow = ws + OFF_SHG + (size_t)b * kH * kS + (size_t)hh * kS + seg * 16;
  __syncthreads();

  // prologue: prefetch gates r,z for the first iteration
  float4 qr[4], qz[4];
#pragma unroll
  for (int q = 0; q < 4; ++q) qr[q] = *reinterpret_cast<const float4*>(whpr + 4 * q);
#pragma unroll
  for (int q = 0; q < 4; ++q) qz[q] = *reinterpret_cast<const float4*>(whpz + 4 * q);

  for (int t = 0; t < kT; ++t) {
    float4 w1b[4], shb[4], w2b[4];

    // ---- PH_A: gi (own li) + gh partials (r/z prefetched, n in-phase) ----
    float gi0, gi1, gi2;
    {
      float4 qn[4];
#pragma unroll
      for (int q = 0; q < 4; ++q) qn[q] = *reinterpret_cast<const float4*>(whpn + 4 * q);
      float v_dec = dec_l[lane & 7];
      gi0 = bc_l[li]; gi1 = bc_l[kH + li]; gi2 = bc_l[2 * kH + li];
#pragma unroll
      for (int i = 0; i < 8; ++i) {
        float d = rlane(v_dec, i);
        gi0 = fmaf(wcr0[i], d, gi0);
        gi1 = fmaf(wcr1[i], d, gi1);
        gi2 = fmaf(wcr2[i], d, gi2);
      }
      float a0 = 0.f, a1 = 0.f;
#pragma unroll
      for (int q = 0; q < 4; ++q) {
        float4 w0 = qr[q], w1 = qz[q];
        float h0 = rlane(h_prev, 4 * q + 0), h1 = rlane(h_prev, 4 * q + 1);
        float h2 = rlane(h_prev, 4 * q + 2), h3 = rlane(h_prev, 4 * q + 3);
        a0 = fmaf(h0, w0.x, a0); a1 = fmaf(h0, w1.x, a1);
        a0 = fmaf(h1, w0.y, a0); a1 = fmaf(h1, w1.y, a1);
        a0 = fmaf(h2, w0.z, a0); a1 = fmaf(h2, w1.z, a1);
        a0 = fmaf(h3, w0.w, a0); a1 = fmaf(h3, w1.w, a1);
      }
      // issue w1 prefetch for PH_B
#pragma unroll
      for (int q = 0; q < 4; ++q) w1b[q] = *reinterpret_cast<const float4*>(w1row + 4 * q);
      float a2x = 0.f, a2y = 0.f;
#pragma unroll
      for (int q = 0; q < 4; ++q) {
        float4 w = qn[q];
        a2x = fmaf(rlane(h_prev, 4 * q + 0), w.x, a2x);
        a2y = fmaf(rlane(h_prev, 4 * q + 1), w.y, a2y);
        a2x = fmaf(rlane(h_prev, 4 * q + 2), w.z, a2x);
        a2y = fmaf(rlane(h_prev, 4 * q + 3), w.w, a2y);
      }
      pg_l[(seg * 3 + 0) * kS + hh] = a0;
      pg_l[(seg * 3 + 1) * kS + hh] = a1;
      pg_l[(seg * 3 + 2) * kS + hh] = a2x + a2y;
    }
    lds_barrier();

    // ---- PH_B: GRU (replicated per-thread) + u1 partials (w1b prefetched) ----
    {
      float gh0, gh1, gh2;
      {
        float p00 = pg_l[(0*3+0)*kS+li], p10 = pg_l[(1*3+0)*kS+li];
        float p20 = pg_l[(2*3+0)*kS+li], p30 = pg_l[(3*3+0)*kS+li];
        float p40 = pg_l[(4*3+0)*kS+li], p50 = pg_l[(5*3+0)*kS+li];
        float p60 = pg_l[(6*3+0)*kS+li], p70 = pg_l[(7*3+0)*kS+li];
        gh0 = bh_l[li] + (((p00+p10)+(p20+p30)) + ((p40+p50)+(p60+p70)));
        float p01 = pg_l[(0*3+1)*kS+li], p11 = pg_l[(1*3+1)*kS+li];
        float p21 = pg_l[(2*3+1)*kS+li], p31 = pg_l[(3*3+1)*kS+li];
        float p41 = pg_l[(4*3+1)*kS+li], p51 = pg_l[(5*3+1)*kS+li];
        float p61 = pg_l[(6*3+1)*kS+li], p71 = pg_l[(7*3+1)*kS+li];
        gh1 = bh_l[kH + li] + (((p01+p11)+(p21+p31)) + ((p41+p51)+(p61+p71)));
        float p02 = pg_l[(0*3+2)*kS+li], p12 = pg_l[(1*3+2)*kS+li];
        float p22 = pg_l[(2*3+2)*kS+li], p32 = pg_l[(3*3+2)*kS+li];
        float p42 = pg_l[(4*3+2)*kS+li], p52 = pg_l[(5*3+2)*kS+li];
        float p62 = pg_l[(6*3+2)*kS+li], p72 = pg_l[(7*3+2)*kS+li];
        gh2 = bh_l[2*kH + li] + (((p02+p12)+(p22+p32)) + ((p42+p52)+(p62+p72)));
      }
      float r = 1.f / (1.f + __expf(-(gi0 + gh0)));
      float z = 1.f / (1.f + __expf(-(gi1 + gh1)));
      float x = gi2 + r * gh2;
      x = fminf(15.f, fmaxf(-15.f, x));
      float e = __expf(-2.f * x);
      float n = (1.f - e) / (1.f + e);
      float hnew = (1.f - z) * n + z * h_prev;
      h_prev = hnew;
      float acc0 = 0.f, acc1 = 0.f;
#pragma unroll
      for (int q = 0; q < 4; ++q) {
        float4 w = w1b[q];
        acc0 = fmaf(rlane(hnew, 4 * q + 0), w.x, acc0);
        acc1 = fmaf(rlane(hnew, 4 * q + 1), w.y, acc1);
        acc0 = fmaf(rlane(hnew, 4 * q + 2), w.z, acc0);
        acc1 = fmaf(rlane(hnew, 4 * q + 3), w.w, acc1);
      }
      pu_l[seg * kS + hh] = acc0 + acc1;
    }
    lds_barrier();

    // ---- PH_C: attn1 partials (tanh, base1 in LDS); prefetch sh for PH_E ----
    {
#pragma unroll
      for (int q = 0; q < 4; ++q) shb[q] = *reinterpret_cast<const float4*>(shrow + 4 * q);
      float u0 = pu_l[li],        u1 = pu_l[kS + li];
      float u2 = pu_l[2*kS + li], u3 = pu_l[3*kS + li];
      float u4 = pu_l[4*kS + li], u5 = pu_l[5*kS + li];
      float u6 = pu_l[6*kS + li], u7 = pu_l[7*kS + li];
      float v_u1 = (((u0+u1)+(u2+u3)) + ((u4+u5)+(u6+u7)));
      float acc0 = 0.f, acc1 = 0.f;
#pragma unroll
      for (int kk = 0; kk < 16; kk += 2) {
        float xa = base1_l[(seg * 16 + kk) * kS + hh] + rlane(v_u1, kk);
        float xb = base1_l[(seg * 16 + kk + 1) * kS + hh] + rlane(v_u1, kk + 1);
        acc0 = fmaf(rlane(v_vv1, kk), tanh_fast(xa), acc0);
        acc1 = fmaf(rlane(v_vv1, kk + 1), tanh_fast(xb), acc1);
      }
      pa_l[seg * kS + hh] = acc0 + acc1;
    }
    lds_barrier();

    // ---- PH_E: softmax1 exp + seg sums + dytext partials; prefetch w2 ----
    {
#pragma unroll
      for (int q = 0; q < 4; ++q) w2b[q] = *reinterpret_cast<const float4*>(w2row + 4 * q);
      float p0 = pa_l[li],        p1 = pa_l[kS + li];
      float p2 = pa_l[2*kS + li], p3 = pa_l[3*kS + li];
      float p4 = pa_l[4*kS + li], p5 = pa_l[5*kS + li];
      float p6 = pa_l[6*kS + li], p7 = pa_l[7*kS + li];
      float a = (((p0+p1)+(p2+p3)) + ((p4+p5)+(p6+p7)));
      float ee = __expf(fminf(a, 60.f));
      float ssum = ee;
#pragma unroll
      for (int off = 1; off < 16; off <<= 1) ssum += __shfl_xor(ssum, off);
      if ((lane & 15) == 0) wsum_l[seg] = ssum;
      float acc0 = 0.f, acc1 = 0.f;
#pragma unroll
      for (int q = 0; q < 4; ++q) {
        float4 w = shb[q];
        acc0 = fmaf(rlane(ee, 4 * q + 0), w.x, acc0);
        acc1 = fmaf(rlane(ee, 4 * q + 1), w.y, acc1);
        acc0 = fmaf(rlane(ee, 4 * q + 2), w.z, acc0);
        acc1 = fmaf(rlane(ee, 4 * q + 3), w.w, acc1);
      }
      pu_l[seg * kS + hh] = acc0 + acc1;
    }
    lds_barrier();

    // ---- PH_F: u2 partials (w2b prefetched); one thread computes 1/sum ----
    {
      float p0 = pu_l[li],        p1 = pu_l[kS + li];
      float p2 = pu_l[2*kS + li], p3 = pu_l[3*kS + li];
      float p4 = pu_l[4*kS + li], p5 = pu_l[5*kS + li];
      float p6 = pu_l[6*kS + li], p7 = pu_l[7*kS + li];
      float v_dy = (((p0+p1)+(p2+p3)) + ((p4+p5)+(p6+p7)));
      float acc0 = 0.f, acc1 = 0.f;
#pragma unroll
      for (int q = 0; q < 4; ++q) {
        float4 w = w2b[q];
        acc0 = fmaf(rlane(v_dy, 4 * q + 0), w.x, acc0);
        acc1 = fmaf(rlane(v_dy, 4 * q + 1), w.y, acc1);
        acc0 = fmaf(rlane(v_dy, 4 * q + 2), w.z, acc0);
        acc1 = fmaf(rlane(v_dy, 4 * q + 3), w.w, acc1);
      }
      pa_l[seg * kS + hh] = acc0 + acc1;
      if (tid == 0) {
        float s = ((wsum_l[0] + wsum_l[1]) + (wsum_l[2] + wsum_l[3])) +
                  ((wsum_l[4] + wsum_l[5]) + (wsum_l[6] + wsum_l[7]));
        rinv_l[0] = 1.0f / s;
      }
    }
    lds_barrier();

    // ---- PH_G: attn2 partials (tanh, base2 in LDS); prefetch next r,z ----
    {
#pragma unroll
      for (int q = 0; q < 4; ++q) qr[q] = *reinterpret_cast<const float4*>(whpr + 4 * q);
#pragma unroll
      for (int q = 0; q < 4; ++q) qz[q] = *reinterpret_cast<const float4*>(whpz + 4 * q);
      float rin = rinv_l[0];
      float p0 = pa_l[li],        p1 = pa_l[kS + li];
      float p2 = pa_l[2*kS + li], p3 = pa_l[3*kS + li];
      float p4 = pa_l[4*kS + li], p5 = pa_l[5*kS + li];
      float p6 = pa_l[6*kS + li], p7 = pa_l[7*kS + li];
      float v_u2 = ((((p0+p1)+(p2+p3)) + ((p4+p5)+(p6+p7)))) * rin;
      float acc0 = 0.f, acc1 = 0.f;
#pragma unroll
      for (int kk = 0; kk < 16; kk += 2) {
        float xa = base2_l[(seg * 16 + kk) * kS + hh] + rlane(v_u2, kk);
        float xb = base2_l[(seg * 16 + kk + 1) * kS + hh] + rlane(v_u2, kk + 1);
        acc0 = fmaf(rlane(v_vv2, kk), tanh_fast(xa), acc0);
        acc1 = fmaf(rlane(v_vv2, kk + 1), tanh_fast(xb), acc1);
      }
      pu_l[seg * kS + hh] = acc0 + acc1;
    }
    lds_barrier();

    // ---- PH_H: logits, argmax, logsumexp, state update (wave 0 only) ----
    if (tid < 64) {
      int s0 = lane, s1 = lane + 64;
      float l0, l1;
      {
        float q0 = pu_l[s0],        q1 = pu_l[kS + s0];
        float q2 = pu_l[2*kS + s0], q3 = pu_l[3*kS + s0];
        float q4 = pu_l[4*kS + s0], q5 = pu_l[5*kS + s0];
        float q6 = pu_l[6*kS + s0], q7 = pu_l[7*kS + s0];
        l0 = (((q0+q1)+(q2+q3)) + ((q4+q5)+(q6+q7)));
        float r0 = pu_l[s1],        r1 = pu_l[kS + s1];
        float r2 = pu_l[2*kS + s1], r3 = pu_l[3*kS + s1];
        float r4 = pu_l[4*kS + s1], r5 = pu_l[5*kS + s1];
        float r6 = pu_l[6*kS + s1], r7 = pu_l[7*kS + s1];
        l1 = (((r0+r1)+(r2+r3)) + ((r4+r5)+(r6+r7)));
      }
      l0 += (mask_l[s0] > 0.f ? 0.f : -1e30f);
      l1 += (mask_l[s1] > 0.f ? 0.f : -1e30f);
      float es = __expf(l0) + __expf(l1);
      float mv; int mi;
      if (l1 > l0) { mv = l1; mi = s1; } else { mv = l0; mi = s0; }
#pragma unroll
      for (int off = 1; off < 64; off <<= 1) {
        float ov = __shfl_xor(mv, off);
        int oi = __shfl_xor(mi, off);
        if (ov > mv || (ov == mv && oi < mi)) { mv = ov; mi = oi; }
        es += __shfl_xor(es, off);
      }
      if (lane == 0) {
        out[b * kT + t] = (float)mi;
        out[kB * kT + b * kT + t] = mv - __logf(es);
        mask_l[mi] = 0.f;
      }
      if (lane < kSS) dec_l[lane] = stat_l[lane * kS + mi];
    }
    lds_barrier();
  }
}

}  // namespace

extern "C" void kernel_launch(void* const* d_in, const int* in_sizes, int n_in,
                              void* d_out, int out_size, void* d_ws, size_t ws_size,
                              hipStream_t stream) {
  const float* stat_g = (const float*)d_in[0];
  const float* dyn_g  = (const float*)d_in[1];
  const float* W_s   = (const float*)d_in[3];
  const float* b_s   = (const float*)d_in[4];
  const float* W_d   = (const float*)d_in[5];
  const float* b_d   = (const float*)d_in[6];
  const float* W_dec = (const float*)d_in[7];
  const float* b_dec = (const float*)d_in[8];
  const float* vv1   = (const float*)d_in[9];
  const float* ww1   = (const float*)d_in[10];
  const float* vv2   = (const float*)d_in[11];
  const float* ww2   = (const float*)d_in[12];
  const float* W_ih  = (const float*)d_in[13];
  const float* W_hh  = (const float*)d_in[14];
  const float* b_ih  = (const float*)d_in[15];
  const float* b_hh  = (const float*)d_in[16];

  float* ws = (float*)d_ws;
  float* out = (float*)d_out;

  prep_w<<<1, 256, 0, stream>>>(W_ih, W_dec, b_ih, b_dec, ws);
  prep_sh<<<kB, 256, 0, stream>>>(stat_g, dyn_g, W_s, b_s, W_d, b_d, ws);
  prep_base<<<dim3(kB, 2), 256, 0, stream>>>(ww1, ww2, ws);
  ptrnet_main<<<kB, 1024, 0, stream>>>(stat_g, dyn_g, vv1, vv2, b_hh, W_hh,
                                       ww1, ww2, ws, out);
}

// Round 13
// 2004.129 us; speedup vs baseline: 1.0337x; 1.0337x over previous
//
#include <hip/hip_runtime.h>

// DRL4SSP pointer-network decoder, MI355X (gfx950).
// 64 batches -> 64 blocks x 1024 threads (16 waves, 4 waves/SIMD), 127 steps,
// 7 lgkm-only barriers/step. Fits the allocator's hard 64-VGPR budget:
//  - gi precomputed for ALL 129 possible decoder inputs (gi_all[b][ptr][384]);
//    the loop just loads 3 floats indexed by the previous argmax.
//  - all weight streams (WhhT gates, w1hT, w2dT, shT) are 16 coalesced
//    strided scalar loads consumed in-phase; no cross-barrier reg buffers.
//  - base1/base2/partials in 154 KB static LDS.

namespace {

constexpr int kB = 64, kSS = 8, kDS = 4, kH = 128, kS = 128, kT = 127, kG3 = 384;

// workspace layout (float offsets)
constexpr size_t OFF_BASE1 = 0;                                   // 1,048,576
constexpr size_t OFF_BASE2 = OFF_BASE1 + (size_t)kB * kH * kS;    // 1,048,576
constexpr size_t OFF_SHT   = OFF_BASE2 + (size_t)kB * kH * kS;    // static_h^T [b][s][h]
constexpr size_t OFF_WHHT  = OFF_SHT   + (size_t)kB * kS * kH;    // WhhT [3][128][128]
constexpr size_t OFF_W1HT  = OFF_WHHT  + (size_t)3 * kH * kH;
constexpr size_t OFF_W2DT  = OFF_W1HT  + (size_t)kH * kH;
constexpr size_t OFF_WCT   = OFF_W2DT  + (size_t)kH * kH;         // WcombT [8][384]
constexpr size_t OFF_BCOMB = OFF_WCT   + (size_t)kSS * kG3;
constexpr size_t OFF_SHG   = OFF_BCOMB + kG3;                     // scratch (prep only)
constexpr size_t OFF_DHG   = OFF_SHG   + (size_t)kB * kH * kS;    // scratch (prep only)
// gi_all overlays the retired SHG/DHG scratch (prep_gi runs after prep_base)
constexpr size_t OFF_GIALL = OFF_SHG;                             // [b][129][384]
// total = OFF_GIALL + 64*129*384 = 6,404,620 floats (~25.6 MB)

// static-LDS layout (float offsets)
constexpr int L_BASE1 = 0;        // 16384
constexpr int L_BASE2 = 16384;    // 16384
constexpr int L_BH    = 32768;    // 384
constexpr int L_PG    = 33152;    // 3072  [8 seg][3 gate][128]
constexpr int L_PU    = 36224;    // 1024
constexpr int L_PA    = 37248;    // 1024
constexpr int L_MASK  = 38272;    // 128
constexpr int L_WSUM  = 38400;    // 8
constexpr int L_RINV  = 38408;    // 1
constexpr int LDS_FLOATS = 38412; // 153,648 B

__device__ __forceinline__ float rlane(float v, int l) {
  return __uint_as_float(__builtin_amdgcn_readlane(__float_as_uint(v), (unsigned)l));
}

__device__ __forceinline__ float tanh_fast(float x) {
  // identical to the round-1..12 (passing) formula — trajectory-sensitive
  x = fminf(15.f, fmaxf(-15.f, x));
  float e = __expf(-2.f * x);
  return (1.f - e) * __builtin_amdgcn_rcpf(1.f + e);
}

__device__ __forceinline__ void lds_barrier() {
  asm volatile("s_waitcnt lgkmcnt(0)" ::: "memory");
  __builtin_amdgcn_s_barrier();
}

// ---------------- precompute kernels ----------------

__global__ void prep_w(const float* __restrict__ W_ih, const float* __restrict__ W_dec,
                       const float* __restrict__ b_ih, const float* __restrict__ b_dec,
                       const float* __restrict__ W_hh,
                       const float* __restrict__ ww1, const float* __restrict__ ww2,
                       float* __restrict__ ws) {
  const int tid = threadIdx.x;
  float* WcT   = ws + OFF_WCT;    // [i][j] = sum_k W_ih[j,k] W_dec[k,i]
  float* bcomb = ws + OFF_BCOMB;
  float* whhT  = ws + OFF_WHHT;   // [g][k][j]
  float* w1hT  = ws + OFF_W1HT;   // [k][h]
  float* w2dT  = ws + OFF_W2DT;
  for (int idx = tid; idx < kSS * kG3; idx += 256) {
    int i = idx / kG3, j = idx % kG3;
    float acc = 0.f;
    for (int k = 0; k < kH; ++k) acc = fmaf(W_ih[j * kH + k], W_dec[k * kSS + i], acc);
    WcT[idx] = acc;
  }
  for (int j = tid; j < kG3; j += 256) {
    float acc = b_ih[j];
    for (int k = 0; k < kH; ++k) acc = fmaf(W_ih[j * kH + k], b_dec[k], acc);
    bcomb[j] = acc;
  }
  for (int idx = tid; idx < 3 * kH * kH; idx += 256) {
    int g = idx >> 14, r = idx & 16383, k = r >> 7, j = r & 127;
    whhT[idx] = W_hh[g * kH * kH + j * kH + k];
  }
  for (int idx = tid; idx < kH * kH; idx += 256) {
    int k = idx >> 7, h = idx & 127;
    w1hT[idx] = ww1[h * kG3 + 2 * kH + k];  // w1h = ww1[:, 2H:3H]
    w2dT[idx] = ww2[h * kG3 + kH + k];      // w2d = ww2[:, H:2H]
  }
}

__global__ void prep_sh(const float* __restrict__ stat_g, const float* __restrict__ dyn_g,
                        const float* __restrict__ W_s, const float* __restrict__ b_s,
                        const float* __restrict__ W_d, const float* __restrict__ b_d,
                        float* __restrict__ ws) {
  const int b = blockIdx.x, tid = threadIdx.x;
  float* sh_g = ws + OFF_SHG;
  float* dh_g = ws + OFF_DHG;
  float* shT  = ws + OFF_SHT;
  const float* sb = stat_g + (size_t)b * kSS * kS;
  const float* db = dyn_g + (size_t)b * kDS * kS;
  for (int idx = tid; idx < kH * kS; idx += 256) {
    int k = idx >> 7, s = idx & 127;
    float acc = b_s[k];
#pragma unroll
    for (int i = 0; i < kSS; ++i) acc = fmaf(W_s[k * kSS + i], sb[i * kS + s], acc);
    sh_g[(size_t)b * kH * kS + idx] = acc;
    float accd = b_d[k];
#pragma unroll
    for (int i = 0; i < kDS; ++i) accd = fmaf(W_d[k * kDS + i], db[i * kS + s], accd);
    dh_g[(size_t)b * kH * kS + idx] = accd;
  }
  for (int idx = tid; idx < kS * kH; idx += 256) {
    int s = idx >> 7, k = idx & 127;
    float acc = b_s[k];
#pragma unroll
    for (int i = 0; i < kSS; ++i) acc = fmaf(W_s[k * kSS + i], sb[i * kS + s], acc);
    shT[(size_t)b * kS * kH + idx] = acc;
  }
}

__global__ void prep_base(const float* __restrict__ ww1, const float* __restrict__ ww2,
                          float* __restrict__ ws) {
  const int b = blockIdx.x, which = blockIdx.y, tid = threadIdx.x;
  const float* sh_g = ws + OFF_SHG + (size_t)b * kH * kS;
  const float* dh_g = ws + OFF_DHG + (size_t)b * kH * kS;
  const float* ww = which ? ww2 : ww1;
  const int dh_off = which ? 2 * kH : kH;
  float* dst = ws + (which ? OFF_BASE2 : OFF_BASE1) + (size_t)b * kH * kS;
  for (int idx = tid; idx < kH * kS / 4; idx += 256) {
    int h = idx >> 5, sq = idx & 31;
    const float* wrow = ww + h * kG3;
    float4 acc = make_float4(0.f, 0.f, 0.f, 0.f);
#pragma unroll 8
    for (int k = 0; k < kH; ++k) {
      float w = wrow[k];
      float4 v = *reinterpret_cast<const float4*>(sh_g + k * kS + sq * 4);
      acc.x = fmaf(w, v.x, acc.x); acc.y = fmaf(w, v.y, acc.y);
      acc.z = fmaf(w, v.z, acc.z); acc.w = fmaf(w, v.w, acc.w);
    }
#pragma unroll 8
    for (int k = 0; k < kH; ++k) {
      float w = wrow[dh_off + k];
      float4 v = *reinterpret_cast<const float4*>(dh_g + k * kS + sq * 4);
      acc.x = fmaf(w, v.x, acc.x); acc.y = fmaf(w, v.y, acc.y);
      acc.z = fmaf(w, v.z, acc.z); acc.w = fmaf(w, v.w, acc.w);
    }
    *reinterpret_cast<float4*>(dst + h * kS + sq * 4) = acc;
  }
}

// gi_all[b][s][j] = bcomb[j] + sum_i WcT[i][j] * static[b][i][s]; slot s=128 is
// the dec_in=0 case (step 0). Runs AFTER prep_base (overlays SHG/DHG scratch).
__global__ void prep_gi(const float* __restrict__ stat_g, float* __restrict__ ws) {
  const int b = blockIdx.x, tid = threadIdx.x;
  const float* WcT = ws + OFF_WCT;
  const float* bcomb = ws + OFF_BCOMB;
  float* gia = ws + OFF_GIALL + (size_t)b * (kS + 1) * kG3;
  const float* sb = stat_g + (size_t)b * kSS * kS;
  for (int idx = tid; idx < (kS + 1) * kG3; idx += 256) {
    int s = idx / kG3, j = idx % kG3;
    float acc = bcomb[j];
#pragma unroll
    for (int i = 0; i < kSS; ++i) {
      float d = (s < kS) ? sb[i * kS + s] : 0.f;
      acc = fmaf(WcT[i * kG3 + j], d, acc);
    }
    gia[idx] = acc;
  }
}

// ---------------- main sequential kernel ----------------

__global__ __launch_bounds__(1024) void ptrnet_main(
    const float* __restrict__ dyn_g,
    const float* __restrict__ vv1_g, const float* __restrict__ vv2_g,
    const float* __restrict__ bhh_g,
    const float* __restrict__ ws, float* __restrict__ out) {
  __shared__ float sm[LDS_FLOATS];
  __shared__ int ptr_sh;
  const int b = blockIdx.x;
  const int tid = threadIdx.x;
  const int hh = tid & 127;            // output/s column
  const int seg = tid >> 7;            // 0..7: 16-row chunk
  const int lane = tid & 63;
  const int li = seg * 16 + (hh & 15); // owned 128-index; 16-periodic in lanes

  float* base1_l = sm + L_BASE1;
  float* base2_l = sm + L_BASE2;
  float* bh_l    = sm + L_BH;
  float* pg_l    = sm + L_PG;
  float* pu_l    = sm + L_PU;
  float* pa_l    = sm + L_PA;
  float* mask_l  = sm + L_MASK;
  float* wsum_l  = sm + L_WSUM;
  float* rinv_l  = sm + L_RINV;

  // ---- LDS init (one-time) ----
  {
    const float4* b1g = reinterpret_cast<const float4*>(ws + OFF_BASE1 + (size_t)b * kH * kS);
    const float4* b2g = reinterpret_cast<const float4*>(ws + OFF_BASE2 + (size_t)b * kH * kS);
    float4* b1l = reinterpret_cast<float4*>(base1_l);
    float4* b2l = reinterpret_cast<float4*>(base2_l);
    for (int i = tid; i < kH * kS / 4; i += 1024) { b1l[i] = b1g[i]; b2l[i] = b2g[i]; }
    if (tid < kG3) bh_l[tid] = bhh_g[tid];
    if (tid < kS)
      mask_l[tid] = (tid == 0 || dyn_g[(size_t)b * kDS * kS + tid] != 0.f) ? 0.f : 1.f;
    if (tid == 0) ptr_sh = kS;   // slot 128 == dec_in = 0 (step 0)
  }

  const float v_vv1 = vv1_g[li], v_vv2 = vv2_g[li];
  float h_prev = 0.f;

  // coalesced stream bases (lane varies hh / li -> stride-1 across lanes)
  const float* whT  = ws + OFF_WHHT + (size_t)(seg * 16) * kH + hh;  // +g*16384
  const float* w1T  = ws + OFF_W1HT + (size_t)(seg * 16) * kH + hh;
  const float* w2T  = ws + OFF_W2DT + (size_t)(seg * 16) * kH + hh;
  const float* shT  = ws + OFF_SHT + (size_t)b * kS * kH + (size_t)(seg * 16) * kH + hh;
  const float* gia  = ws + OFF_GIALL + (size_t)b * (kS + 1) * kG3;
  __syncthreads();

  for (int t = 0; t < kT; ++t) {
    // ---- PH_A: issue gi loads; gh partials (3 gates, coalesced streams) ----
    float gi0, gi1, gi2;
    {
      const float* gp = gia + (size_t)ptr_sh * kG3 + li;
      gi0 = gp[0]; gi1 = gp[kH]; gi2 = gp[2 * kH];   // consumed in PH_B
      float c0[16], c1[16];
#pragma unroll
      for (int q = 0; q < 16; ++q) c0[q] = whT[q * kH];               // gate r
#pragma unroll
      for (int q = 0; q < 16; ++q) c1[q] = whT[kH * kH + q * kH];     // gate z
      float a0 = 0.f, a1 = 0.f;
#pragma unroll
      for (int q = 0; q < 16; ++q) {
        float hv = rlane(h_prev, q);
        a0 = fmaf(hv, c0[q], a0);
        a1 = fmaf(hv, c1[q], a1);
      }
#pragma unroll
      for (int q = 0; q < 16; ++q) c0[q] = whT[2 * kH * kH + q * kH]; // gate n
      float a2x = 0.f, a2y = 0.f;
#pragma unroll
      for (int q = 0; q < 16; q += 2) {
        a2x = fmaf(rlane(h_prev, q), c0[q], a2x);
        a2y = fmaf(rlane(h_prev, q + 1), c0[q + 1], a2y);
      }
      pg_l[(seg * 3 + 0) * kS + hh] = a0;
      pg_l[(seg * 3 + 1) * kS + hh] = a1;
      pg_l[(seg * 3 + 2) * kS + hh] = a2x + a2y;
    }
    lds_barrier();

    // ---- PH_B: GRU (replicated per-thread) + u1 partials (w1 streamed) ----
    {
      float b0[16];
#pragma unroll
      for (int q = 0; q < 16; ++q) b0[q] = w1T[q * kH];
      float gh0, gh1, gh2;
      {
        float p00 = pg_l[(0*3+0)*kS+li], p10 = pg_l[(1*3+0)*kS+li];
        float p20 = pg_l[(2*3+0)*kS+li], p30 = pg_l[(3*3+0)*kS+li];
        float p40 = pg_l[(4*3+0)*kS+li], p50 = pg_l[(5*3+0)*kS+li];
        float p60 = pg_l[(6*3+0)*kS+li], p70 = pg_l[(7*3+0)*kS+li];
        gh0 = bh_l[li] + (((p00+p10)+(p20+p30)) + ((p40+p50)+(p60+p70)));
        float p01 = pg_l[(0*3+1)*kS+li], p11 = pg_l[(1*3+1)*kS+li];
        float p21 = pg_l[(2*3+1)*kS+li], p31 = pg_l[(3*3+1)*kS+li];
        float p41 = pg_l[(4*3+1)*kS+li], p51 = pg_l[(5*3+1)*kS+li];
        float p61 = pg_l[(6*3+1)*kS+li], p71 = pg_l[(7*3+1)*kS+li];
        gh1 = bh_l[kH + li] + (((p01+p11)+(p21+p31)) + ((p41+p51)+(p61+p71)));
        float p02 = pg_l[(0*3+2)*kS+li], p12 = pg_l[(1*3+2)*kS+li];
        float p22 = pg_l[(2*3+2)*kS+li], p32 = pg_l[(3*3+2)*kS+li];
        float p42 = pg_l[(4*3+2)*kS+li], p52 = pg_l[(5*3+2)*kS+li];
        float p62 = pg_l[(6*3+2)*kS+li], p72 = pg_l[(7*3+2)*kS+li];
        gh2 = bh_l[2*kH + li] + (((p02+p12)+(p22+p32)) + ((p42+p52)+(p62+p72)));
      }
      float r = 1.f / (1.f + __expf(-(gi0 + gh0)));
      float z = 1.f / (1.f + __expf(-(gi1 + gh1)));
      float x = gi2 + r * gh2;
      x = fminf(15.f, fmaxf(-15.f, x));
      float e = __expf(-2.f * x);
      float n = (1.f - e) / (1.f + e);
      float hnew = (1.f - z) * n + z * h_prev;
      h_prev = hnew;
      float acc0 = 0.f, acc1 = 0.f;
#pragma unroll
      for (int q = 0; q < 16; q += 2) {
        acc0 = fmaf(rlane(hnew, q), b0[q], acc0);
        acc1 = fmaf(rlane(hnew, q + 1), b0[q + 1], acc1);
      }
      pu_l[seg * kS + hh] = acc0 + acc1;
    }
    lds_barrier();

    // ---- PH_C: attn1 partials (tanh over 16 h-rows, base1 in LDS) ----
    {
      float u0 = pu_l[li],        u1 = pu_l[kS + li];
      float u2 = pu_l[2*kS + li], u3 = pu_l[3*kS + li];
      float u4 = pu_l[4*kS + li], u5 = pu_l[5*kS + li];
      float u6 = pu_l[6*kS + li], u7 = pu_l[7*kS + li];
      float v_u1 = (((u0+u1)+(u2+u3)) + ((u4+u5)+(u6+u7)));
      float acc0 = 0.f, acc1 = 0.f;
#pragma unroll
      for (int kk = 0; kk < 16; kk += 2) {
        float xa = base1_l[(seg * 16 + kk) * kS + hh] + rlane(v_u1, kk);
        float xb = base1_l[(seg * 16 + kk + 1) * kS + hh] + rlane(v_u1, kk + 1);
        acc0 = fmaf(rlane(v_vv1, kk), tanh_fast(xa), acc0);
        acc1 = fmaf(rlane(v_vv1, kk + 1), tanh_fast(xb), acc1);
      }
      pa_l[seg * kS + hh] = acc0 + acc1;
    }
    lds_barrier();

    // ---- PH_E: softmax1 exp + seg sums + dytext partials (sh streamed) ----
    {
      float b0[16];
#pragma unroll
      for (int q = 0; q < 16; ++q) b0[q] = shT[q * kH];
      float p0 = pa_l[li],        p1 = pa_l[kS + li];
      float p2 = pa_l[2*kS + li], p3 = pa_l[3*kS + li];
      float p4 = pa_l[4*kS + li], p5 = pa_l[5*kS + li];
      float p6 = pa_l[6*kS + li], p7 = pa_l[7*kS + li];
      float a = (((p0+p1)+(p2+p3)) + ((p4+p5)+(p6+p7)));
      float ee = __expf(fminf(a, 60.f));
      float ssum = ee;
#pragma unroll
      for (int off = 1; off < 16; off <<= 1) ssum += __shfl_xor(ssum, off);
      if ((lane & 15) == 0) wsum_l[seg] = ssum;
      float acc0 = 0.f, acc1 = 0.f;
#pragma unroll
      for (int q = 0; q < 16; q += 2) {
        acc0 = fmaf(rlane(ee, q), b0[q], acc0);
        acc1 = fmaf(rlane(ee, q + 1), b0[q + 1], acc1);
      }
      pu_l[seg * kS + hh] = acc0 + acc1;
    }
    lds_barrier();

    // ---- PH_F: u2 partials (w2 streamed); one thread computes 1/sum ----
    {
      float b0[16];
#pragma unroll
      for (int q = 0; q < 16; ++q) b0[q] = w2T[q * kH];
      float p0 = pu_l[li],        p1 = pu_l[kS + li];
      float p2 = pu_l[2*kS + li], p3 = pu_l[3*kS + li];
      float p4 = pu_l[4*kS + li], p5 = pu_l[5*kS + li];
      float p6 = pu_l[6*kS + li], p7 = pu_l[7*kS + li];
      float v_dy = (((p0+p1)+(p2+p3)) + ((p4+p5)+(p6+p7)));
      float acc0 = 0.f, acc1 = 0.f;
#pragma unroll
      for (int q = 0; q < 16; q += 2) {
        acc0 = fmaf(rlane(v_dy, q), b0[q], acc0);
        acc1 = fmaf(rlane(v_dy, q + 1), b0[q + 1], acc1);
      }
      pa_l[seg * kS + hh] = acc0 + acc1;
      if (tid == 0) {
        float s = ((wsum_l[0] + wsum_l[1]) + (wsum_l[2] + wsum_l[3])) +
                  ((wsum_l[4] + wsum_l[5]) + (wsum_l[6] + wsum_l[7]));
        rinv_l[0] = 1.0f / s;
      }
    }
    lds_barrier();

    // ---- PH_G: attn2 partials (tanh over 16 h-rows, base2 in LDS) ----
    {
      float rin = rinv_l[0];
      float p0 = pa_l[li],        p1 = pa_l[kS + li];
      float p2 = pa_l[2*kS + li], p3 = pa_l[3*kS + li];
      float p4 = pa_l[4*kS + li], p5 = pa_l[5*kS + li];
      float p6 = pa_l[6*kS + li], p7 = pa_l[7*kS + li];
      float v_u2 = ((((p0+p1)+(p2+p3)) + ((p4+p5)+(p6+p7)))) * rin;
      float acc0 = 0.f, acc1 = 0.f;
#pragma unroll
      for (int kk = 0; kk < 16; kk += 2) {
        float xa = base2_l[(seg * 16 + kk) * kS + hh] + rlane(v_u2, kk);
        float xb = base2_l[(seg * 16 + kk + 1) * kS + hh] + rlane(v_u2, kk + 1);
        acc0 = fmaf(rlane(v_vv2, kk), tanh_fast(xa), acc0);
        acc1 = fmaf(rlane(v_vv2, kk + 1), tanh_fast(xb), acc1);
      }
      pu_l[seg * kS + hh] = acc0 + acc1;
    }
    lds_barrier();

    // ---- PH_H: logits, argmax, logsumexp, state update (wave 0 only) ----
    if (tid < 64) {
      int s0 = lane, s1 = lane + 64;
      float l0, l1;
      {
        float q0 = pu_l[s0],        q1 = pu_l[kS + s0];
        float q2 = pu_l[2*kS + s0], q3 = pu_l[3*kS + s0];
        float q4 = pu_l[4*kS + s0], q5 = pu_l[5*kS + s0];
        float q6 = pu_l[6*kS + s0], q7 = pu_l[7*kS + s0];
        l0 = (((q0+q1)+(q2+q3)) + ((q4+q5)+(q6+q7)));
        float r0 = pu_l[s1],        r1 = pu_l[kS + s1];
        float r2 = pu_l[2*kS + s1], r3 = pu_l[3*kS + s1];
        float r4 = pu_l[4*kS + s1], r5 = pu_l[5*kS + s1];
        float r6 = pu_l[6*kS + s1], r7 = pu_l[7*kS + s1];
        l1 = (((r0+r1)+(r2+r3)) + ((r4+r5)+(r6+r7)));
      }
      l0 += (mask_l[s0] > 0.f ? 0.f : -1e30f);
      l1 += (mask_l[s1] > 0.f ? 0.f : -1e30f);
      float es = __expf(l0) + __expf(l1);
      float mv; int mi;
      if (l1 > l0) { mv = l1; mi = s1; } else { mv = l0; mi = s0; }
#pragma unroll
      for (int off = 1; off < 64; off <<= 1) {
        float ov = __shfl_xor(mv, off);
        int oi = __shfl_xor(mi, off);
        if (ov > mv || (ov == mv && oi < mi)) { mv = ov; mi = oi; }
        es += __shfl_xor(es, off);
      }
      if (lane == 0) {
        out[b * kT + t] = (float)mi;
        out[kB * kT + b * kT + t] = mv - __logf(es);
        mask_l[mi] = 0.f;
        ptr_sh = mi;
      }
    }
    lds_barrier();
  }
}

}  // namespace

extern "C" void kernel_launch(void* const* d_in, const int* in_sizes, int n_in,
                              void* d_out, int out_size, void* d_ws, size_t ws_size,
                              hipStream_t stream) {
  const float* stat_g = (const float*)d_in[0];
  const float* dyn_g  = (const float*)d_in[1];
  const float* W_s   = (const float*)d_in[3];
  const float* b_s   = (const float*)d_in[4];
  const float* W_d   = (const float*)d_in[5];
  const float* b_d   = (const float*)d_in[6];
  const float* W_dec = (const float*)d_in[7];
  const float* b_dec = (const float*)d_in[8];
  const float* vv1   = (const float*)d_in[9];
  const float* ww1   = (const float*)d_in[10];
  const float* vv2   = (const float*)d_in[11];
  const float* ww2   = (const float*)d_in[12];
  const float* W_ih  = (const float*)d_in[13];
  const float* W_hh  = (const float*)d_in[14];
  const float* b_ih  = (const float*)d_in[15];
  const float* b_hh  = (const float*)d_in[16];

  float* ws = (float*)d_ws;
  float* out = (float*)d_out;

  prep_w<<<1, 256, 0, stream>>>(W_ih, W_dec, b_ih, b_dec, W_hh, ww1, ww2, ws);
  prep_sh<<<kB, 256, 0, stream>>>(stat_g, dyn_g, W_s, b_s, W_d, b_d, ws);
  prep_base<<<dim3(kB, 2), 256, 0, stream>>>(ww1, ww2, ws);
  prep_gi<<<kB, 256, 0, stream>>>(stat_g, ws);
  ptrnet_main<<<kB, 1024, 0, stream>>>(dyn_g, vv1, vv2, b_hh, ws, out);
}

// Round 14
// 1902.915 us; speedup vs baseline: 1.0887x; 1.0532x over previous
//
#include <hip/hip_runtime.h>

// DRL4SSP pointer-network decoder, MI355X (gfx950).
// 64 batches -> 64 blocks x 512 threads (128-VGPR budget per the measured
// allocator rule VGPR=65536/threads), 127 steps, 7 lgkm-only barriers/step.
// R9 chassis + gi_all table (gi for all 129 possible pointers precomputed) +
// h broadcast via ds_read_b128 (replaces readlane chains in PH_A).

namespace {

constexpr int kB = 64, kSS = 8, kDS = 4, kH = 128, kS = 128, kT = 127, kG3 = 384;

// workspace layout (float offsets)
constexpr size_t OFF_BASE1 = 0;
constexpr size_t OFF_BASE2 = OFF_BASE1 + (size_t)kB * kH * kS;
constexpr size_t OFF_SHT   = OFF_BASE2 + (size_t)kB * kH * kS;   // static_h^T [b][s][h]
constexpr size_t OFF_W1HT  = OFF_SHT   + (size_t)kB * kS * kH;   // [k][h]
constexpr size_t OFF_W2DT  = OFF_W1HT  + (size_t)kH * kH;
constexpr size_t OFF_WCT   = OFF_W2DT  + (size_t)kH * kH;        // WcombT [8][384]
constexpr size_t OFF_BCOMB = OFF_WCT   + (size_t)kSS * kG3;
constexpr size_t OFF_SHG   = OFF_BCOMB + kG3;                    // prep scratch
constexpr size_t OFF_DHG   = OFF_SHG   + (size_t)kB * kH * kS;   // prep scratch
constexpr size_t OFF_GIALL = OFF_SHG;                            // overlay: [b][129][384]
// total ~ 6.35M floats (25.4 MB)

// static-LDS layout (float offsets)
constexpr int L_BASE1 = 0;        // 16384
constexpr int L_BASE2 = 16384;    // 16384
constexpr int L_BH    = 32768;    // 384
constexpr int L_HL    = 33152;    // 128
constexpr int L_PG    = 33280;    // 1536  [4 seg][3 gate][128]
constexpr int L_PU    = 34816;    // 512
constexpr int L_PA    = 35328;    // 512
constexpr int L_MASK  = 35840;    // 128
constexpr int L_WSUM  = 35968;    // 4
constexpr int L_RINV  = 35972;    // 1
constexpr int LDS_FLOATS = 35976; // 143,904 B

__device__ __forceinline__ float rlane(float v, int l) {
  return __uint_as_float(__builtin_amdgcn_readlane(__float_as_uint(v), (unsigned)l));
}

__device__ __forceinline__ float tanh_fast(float x) {
  // identical to rounds 1..13 (passing) — trajectory-sensitive
  x = fminf(15.f, fmaxf(-15.f, x));
  float e = __expf(-2.f * x);
  return (1.f - e) * __builtin_amdgcn_rcpf(1.f + e);
}

__device__ __forceinline__ void lds_barrier() {
  asm volatile("s_waitcnt lgkmcnt(0)" ::: "memory");
  __builtin_amdgcn_s_barrier();
}

// ---------------- precompute kernels ----------------

__global__ void prep_w(const float* __restrict__ W_ih, const float* __restrict__ W_dec,
                       const float* __restrict__ b_ih, const float* __restrict__ b_dec,
                       const float* __restrict__ ww1, const float* __restrict__ ww2,
                       float* __restrict__ ws) {
  const int tid = threadIdx.x;
  float* WcT   = ws + OFF_WCT;
  float* bcomb = ws + OFF_BCOMB;
  float* w1hT  = ws + OFF_W1HT;
  float* w2dT  = ws + OFF_W2DT;
  for (int idx = tid; idx < kSS * kG3; idx += 256) {
    int i = idx / kG3, j = idx % kG3;
    float acc = 0.f;
    for (int k = 0; k < kH; ++k) acc = fmaf(W_ih[j * kH + k], W_dec[k * kSS + i], acc);
    WcT[idx] = acc;
  }
  for (int j = tid; j < kG3; j += 256) {
    float acc = b_ih[j];
    for (int k = 0; k < kH; ++k) acc = fmaf(W_ih[j * kH + k], b_dec[k], acc);
    bcomb[j] = acc;
  }
  for (int idx = tid; idx < kH * kH; idx += 256) {
    int k = idx >> 7, h = idx & 127;
    w1hT[idx] = ww1[h * kG3 + 2 * kH + k];
    w2dT[idx] = ww2[h * kG3 + kH + k];
  }
}

__global__ void prep_sh(const float* __restrict__ stat_g, const float* __restrict__ dyn_g,
                        const float* __restrict__ W_s, const float* __restrict__ b_s,
                        const float* __restrict__ W_d, const float* __restrict__ b_d,
                        float* __restrict__ ws) {
  const int b = blockIdx.x, tid = threadIdx.x;
  float* sh_g = ws + OFF_SHG;
  float* dh_g = ws + OFF_DHG;
  float* shT  = ws + OFF_SHT;
  const float* sb = stat_g + (size_t)b * kSS * kS;
  const float* db = dyn_g + (size_t)b * kDS * kS;
  for (int idx = tid; idx < kH * kS; idx += 256) {
    int k = idx >> 7, s = idx & 127;
    float acc = b_s[k];
#pragma unroll
    for (int i = 0; i < kSS; ++i) acc = fmaf(W_s[k * kSS + i], sb[i * kS + s], acc);
    sh_g[(size_t)b * kH * kS + idx] = acc;
    float accd = b_d[k];
#pragma unroll
    for (int i = 0; i < kDS; ++i) accd = fmaf(W_d[k * kDS + i], db[i * kS + s], accd);
    dh_g[(size_t)b * kH * kS + idx] = accd;
  }
  for (int idx = tid; idx < kS * kH; idx += 256) {
    int s = idx >> 7, k = idx & 127;
    float acc = b_s[k];
#pragma unroll
    for (int i = 0; i < kSS; ++i) acc = fmaf(W_s[k * kSS + i], sb[i * kS + s], acc);
    shT[(size_t)b * kS * kH + idx] = acc;
  }
}

__global__ void prep_base(const float* __restrict__ ww1, const float* __restrict__ ww2,
                          float* __restrict__ ws) {
  const int b = blockIdx.x, which = blockIdx.y, tid = threadIdx.x;
  const float* sh_g = ws + OFF_SHG + (size_t)b * kH * kS;
  const float* dh_g = ws + OFF_DHG + (size_t)b * kH * kS;
  const float* ww = which ? ww2 : ww1;
  const int dh_off = which ? 2 * kH : kH;
  float* dst = ws + (which ? OFF_BASE2 : OFF_BASE1) + (size_t)b * kH * kS;
  for (int idx = tid; idx < kH * kS / 4; idx += 256) {
    int h = idx >> 5, sq = idx & 31;
    const float* wrow = ww + h * kG3;
    float4 acc = make_float4(0.f, 0.f, 0.f, 0.f);
#pragma unroll 8
    for (int k = 0; k < kH; ++k) {
      float w = wrow[k];
      float4 v = *reinterpret_cast<const float4*>(sh_g + k * kS + sq * 4);
      acc.x = fmaf(w, v.x, acc.x); acc.y = fmaf(w, v.y, acc.y);
      acc.z = fmaf(w, v.z, acc.z); acc.w = fmaf(w, v.w, acc.w);
    }
#pragma unroll 8
    for (int k = 0; k < kH; ++k) {
      float w = wrow[dh_off + k];
      float4 v = *reinterpret_cast<const float4*>(dh_g + k * kS + sq * 4);
      acc.x = fmaf(w, v.x, acc.x); acc.y = fmaf(w, v.y, acc.y);
      acc.z = fmaf(w, v.z, acc.z); acc.w = fmaf(w, v.w, acc.w);
    }
    *reinterpret_cast<float4*>(dst + h * kS + sq * 4) = acc;
  }
}

// gi_all[b][s][j]; slot s=128 is the dec_in=0 case. Runs AFTER prep_base.
__global__ void prep_gi(const float* __restrict__ stat_g, float* __restrict__ ws) {
  const int b = blockIdx.x, tid = threadIdx.x;
  const float* WcT = ws + OFF_WCT;
  const float* bcomb = ws + OFF_BCOMB;
  float* gia = ws + OFF_GIALL + (size_t)b * (kS + 1) * kG3;
  const float* sb = stat_g + (size_t)b * kSS * kS;
  for (int idx = tid; idx < (kS + 1) * kG3; idx += 256) {
    int s = idx / kG3, j = idx % kG3;
    float acc = bcomb[j];
#pragma unroll
    for (int i = 0; i < kSS; ++i) {
      float d = (s < kS) ? sb[i * kS + s] : 0.f;
      acc = fmaf(WcT[i * kG3 + j], d, acc);
    }
    gia[idx] = acc;
  }
}

// ---------------- main sequential kernel ----------------

__global__ __launch_bounds__(512) void ptrnet_main(
    const float* __restrict__ dyn_g,
    const float* __restrict__ vv1_g, const float* __restrict__ vv2_g,
    const float* __restrict__ bhh_g, const float* __restrict__ Whh_g,
    const float* __restrict__ ws, float* __restrict__ out) {
  __shared__ float sm[LDS_FLOATS];
  __shared__ int ptr_sh;
  const int b = blockIdx.x;
  const int tid = threadIdx.x;
  const int hh = tid & 127;
  const int seg = tid >> 7;            // 0..3
  const int lane = tid & 63;
  const int li = seg * 32 + (hh & 31);

  float* base1_l = sm + L_BASE1;
  float* base2_l = sm + L_BASE2;
  float* bh_l    = sm + L_BH;
  float* h_l     = sm + L_HL;
  float* pg_l    = sm + L_PG;
  float* pu_l    = sm + L_PU;
  float* pa_l    = sm + L_PA;
  float* mask_l  = sm + L_MASK;
  float* wsum_l  = sm + L_WSUM;
  float* rinv_l  = sm + L_RINV;

  // ---- LDS init (one-time) ----
  {
    const float4* b1g = reinterpret_cast<const float4*>(ws + OFF_BASE1 + (size_t)b * kH * kS);
    const float4* b2g = reinterpret_cast<const float4*>(ws + OFF_BASE2 + (size_t)b * kH * kS);
    float4* b1l = reinterpret_cast<float4*>(base1_l);
    float4* b2l = reinterpret_cast<float4*>(base2_l);
    for (int i = tid; i < kH * kS / 4; i += 512) { b1l[i] = b1g[i]; b2l[i] = b2g[i]; }
    if (tid < kG3) bh_l[tid] = bhh_g[tid];
    if (tid < kH) h_l[tid] = 0.f;
    if (tid < kS)
      mask_l[tid] = (tid == 0 || dyn_g[(size_t)b * kDS * kS + tid] != 0.f) ? 0.f : 1.f;
    if (tid == 0) ptr_sh = kS;   // slot 128 == dec_in = 0
  }

  const float v_vv1 = vv1_g[li], v_vv2 = vv2_g[li];
  float h_prev = 0.f;

  // stream bases
  const float* whp0 = Whh_g + (size_t)(0 * kH + hh) * kH + seg * 32;  // gate r row
  const float* whp1 = whp0 + (size_t)kH * kH;                         // gate z
  const float* whp2 = whp1 + (size_t)kH * kH;                         // gate n
  const float* w1p = ws + OFF_W1HT + (size_t)(seg * 32) * kH + hh;
  const float* w2p = ws + OFF_W2DT + (size_t)(seg * 32) * kH + hh;
  const float* shp = ws + OFF_SHT + (size_t)b * kS * kH + (size_t)(seg * 32) * kH + hh;
  const float* gia = ws + OFF_GIALL + (size_t)b * (kS + 1) * kG3;
  __syncthreads();

  for (int t = 0; t < kT; ++t) {
    // ---- PH_A: gi loads (for PH_B) + gh partials (h via LDS broadcast) ----
    float gi0, gi1, gi2;
    {
      const float* gp = gia + (size_t)ptr_sh * kG3 + li;
      gi0 = gp[0]; gi1 = gp[kH]; gi2 = gp[2 * kH];
      // h broadcast: 8 x ds_read_b128, all lanes same address
      float4 hq[8];
#pragma unroll
      for (int q = 0; q < 8; ++q)
        hq[q] = *reinterpret_cast<const float4*>(h_l + seg * 32 + 4 * q);
      // gate r
      float a0 = 0.f;
      {
        float4 qw[8];
#pragma unroll
        for (int q = 0; q < 8; ++q) qw[q] = *reinterpret_cast<const float4*>(whp0 + 4 * q);
#pragma unroll
        for (int q = 0; q < 8; ++q) {
          a0 = fmaf(hq[q].x, qw[q].x, a0);
          a0 = fmaf(hq[q].y, qw[q].y, a0);
          a0 = fmaf(hq[q].z, qw[q].z, a0);
          a0 = fmaf(hq[q].w, qw[q].w, a0);
        }
      }
      // gate z
      float a1 = 0.f;
      {
        float4 qw[8];
#pragma unroll
        for (int q = 0; q < 8; ++q) qw[q] = *reinterpret_cast<const float4*>(whp1 + 4 * q);
#pragma unroll
        for (int q = 0; q < 8; ++q) {
          a1 = fmaf(hq[q].x, qw[q].x, a1);
          a1 = fmaf(hq[q].y, qw[q].y, a1);
          a1 = fmaf(hq[q].z, qw[q].z, a1);
          a1 = fmaf(hq[q].w, qw[q].w, a1);
        }
      }
      // gate n (even/odd accumulator split, as R9)
      float a2x = 0.f, a2y = 0.f;
      {
        float4 qw[8];
#pragma unroll
        for (int q = 0; q < 8; ++q) qw[q] = *reinterpret_cast<const float4*>(whp2 + 4 * q);
#pragma unroll
        for (int q = 0; q < 8; ++q) {
          a2x = fmaf(hq[q].x, qw[q].x, a2x);
          a2y = fmaf(hq[q].y, qw[q].y, a2y);
          a2x = fmaf(hq[q].z, qw[q].z, a2x);
          a2y = fmaf(hq[q].w, qw[q].w, a2y);
        }
      }
      pg_l[(seg * 3 + 0) * kS + hh] = a0;
      pg_l[(seg * 3 + 1) * kS + hh] = a1;
      pg_l[(seg * 3 + 2) * kS + hh] = a2x + a2y;
    }
    lds_barrier();

    // ---- PH_B: GRU (replicated per-thread) + u1 partials (w1 streamed) ----
    {
      float b0[8], b1[8], b2[8], b3[8];
#pragma unroll
      for (int j = 0; j < 8; ++j) b0[j] = w1p[j * kH];
#pragma unroll
      for (int j = 0; j < 8; ++j) b1[j] = w1p[(8 + j) * kH];
#pragma unroll
      for (int j = 0; j < 8; ++j) b2[j] = w1p[(16 + j) * kH];
#pragma unroll
      for (int j = 0; j < 8; ++j) b3[j] = w1p[(24 + j) * kH];
      float gh0 = bh_l[li] +
          ((pg_l[(0*3+0)*kS+li] + pg_l[(1*3+0)*kS+li]) + (pg_l[(2*3+0)*kS+li] + pg_l[(3*3+0)*kS+li]));
      float gh1 = bh_l[kH + li] +
          ((pg_l[(0*3+1)*kS+li] + pg_l[(1*3+1)*kS+li]) + (pg_l[(2*3+1)*kS+li] + pg_l[(3*3+1)*kS+li]));
      float gh2 = bh_l[2*kH + li] +
          ((pg_l[(0*3+2)*kS+li] + pg_l[(1*3+2)*kS+li]) + (pg_l[(2*3+2)*kS+li] + pg_l[(3*3+2)*kS+li]));
      float r = 1.f / (1.f + __expf(-(gi0 + gh0)));
      float z = 1.f / (1.f + __expf(-(gi1 + gh1)));
      float x = gi2 + r * gh2;
      x = fminf(15.f, fmaxf(-15.f, x));
      float e = __expf(-2.f * x);
      float n = (1.f - e) / (1.f + e);
      float hnew = (1.f - z) * n + z * h_prev;
      h_prev = hnew;
      if (hh < 32) h_l[li] = hnew;     // publish h for next step's PH_A
      float acc0 = 0.f, acc1 = 0.f;
#pragma unroll
      for (int j = 0; j < 8; ++j) {
        acc0 = fmaf(rlane(hnew, j), b0[j], acc0);
        acc1 = fmaf(rlane(hnew, 8 + j), b1[j], acc1);
      }
#pragma unroll
      for (int j = 0; j < 8; ++j) {
        acc0 = fmaf(rlane(hnew, 16 + j), b2[j], acc0);
        acc1 = fmaf(rlane(hnew, 24 + j), b3[j], acc1);
      }
      pu_l[seg * kS + hh] = acc0 + acc1;
    }
    lds_barrier();

    // ---- PH_C: attn1 partials (tanh over 32 h-rows, base1 in LDS) ----
    {
      float v_u1 = (pu_l[li] + pu_l[kS + li]) + (pu_l[2*kS + li] + pu_l[3*kS + li]);
      float acc0 = 0.f, acc1 = 0.f;
#pragma unroll
      for (int kk = 0; kk < 16; ++kk) {
        float xa = base1_l[(seg * 32 + 2*kk) * kS + hh] + rlane(v_u1, 2*kk);
        float xb = base1_l[(seg * 32 + 2*kk+1) * kS + hh] + rlane(v_u1, 2*kk+1);
        acc0 = fmaf(rlane(v_vv1, 2*kk), tanh_fast(xa), acc0);
        acc1 = fmaf(rlane(v_vv1, 2*kk+1), tanh_fast(xb), acc1);
      }
      pa_l[seg * kS + hh] = acc0 + acc1;
    }
    lds_barrier();

    // ---- PH_E: softmax1 exp + chunk sums + dytext partials (sh streamed) ----
    {
      float b0[8], b1[8], b2[8], b3[8];
#pragma unroll
      for (int j = 0; j < 8; ++j) b0[j] = shp[j * kH];
#pragma unroll
      for (int j = 0; j < 8; ++j) b1[j] = shp[(8 + j) * kH];
#pragma unroll
      for (int j = 0; j < 8; ++j) b2[j] = shp[(16 + j) * kH];
#pragma unroll
      for (int j = 0; j < 8; ++j) b3[j] = shp[(24 + j) * kH];
      float a = (pa_l[li] + pa_l[kS + li]) + (pa_l[2*kS + li] + pa_l[3*kS + li]);
      float ee = __expf(fminf(a, 60.f));
      float ssum = ee;
#pragma unroll
      for (int off = 1; off < 32; off <<= 1) ssum += __shfl_xor(ssum, off);
      if ((lane & 31) == 0) wsum_l[seg] = ssum;
      float acc0 = 0.f, acc1 = 0.f;
#pragma unroll
      for (int j = 0; j < 8; ++j) {
        acc0 = fmaf(rlane(ee, j), b0[j], acc0);
        acc1 = fmaf(rlane(ee, 8 + j), b1[j], acc1);
      }
#pragma unroll
      for (int j = 0; j < 8; ++j) {
        acc0 = fmaf(rlane(ee, 16 + j), b2[j], acc0);
        acc1 = fmaf(rlane(ee, 24 + j), b3[j], acc1);
      }
      pu_l[seg * kS + hh] = acc0 + acc1;
    }
    lds_barrier();

    // ---- PH_F: u2 partials (w2 streamed); one thread computes 1/sum ----
    {
      float b0[8], b1[8], b2[8], b3[8];
#pragma unroll
      for (int j = 0; j < 8; ++j) b0[j] = w2p[j * kH];
#pragma unroll
      for (int j = 0; j < 8; ++j) b1[j] = w2p[(8 + j) * kH];
#pragma unroll
      for (int j = 0; j < 8; ++j) b2[j] = w2p[(16 + j) * kH];
#pragma unroll
      for (int j = 0; j < 8; ++j) b3[j] = w2p[(24 + j) * kH];
      float v_dy = (pu_l[li] + pu_l[kS + li]) + (pu_l[2*kS + li] + pu_l[3*kS + li]);
      float acc0 = 0.f, acc1 = 0.f;
#pragma unroll
      for (int j = 0; j < 8; ++j) {
        acc0 = fmaf(rlane(v_dy, j), b0[j], acc0);
        acc1 = fmaf(rlane(v_dy, 8 + j), b1[j], acc1);
      }
#pragma unroll
      for (int j = 0; j < 8; ++j) {
        acc0 = fmaf(rlane(v_dy, 16 + j), b2[j], acc0);
        acc1 = fmaf(rlane(v_dy, 24 + j), b3[j], acc1);
      }
      pa_l[seg * kS + hh] = acc0 + acc1;
      if (tid == 0) rinv_l[0] = 1.0f / ((wsum_l[0] + wsum_l[1]) + (wsum_l[2] + wsum_l[3]));
    }
    lds_barrier();

    // ---- PH_G: attn2 partials (tanh over 32 h-rows, base2 in LDS) ----
    {
      float rin = rinv_l[0];
      float v_u2 = ((pa_l[li] + pa_l[kS + li]) + (pa_l[2*kS + li] + pa_l[3*kS + li])) * rin;
      float acc0 = 0.f, acc1 = 0.f;
#pragma unroll
      for (int kk = 0; kk < 16; ++kk) {
        float xa = base2_l[(seg * 32 + 2*kk) * kS + hh] + rlane(v_u2, 2*kk);
        float xb = base2_l[(seg * 32 + 2*kk+1) * kS + hh] + rlane(v_u2, 2*kk+1);
        acc0 = fmaf(rlane(v_vv2, 2*kk), tanh_fast(xa), acc0);
        acc1 = fmaf(rlane(v_vv2, 2*kk+1), tanh_fast(xb), acc1);
      }
      pu_l[seg * kS + hh] = acc0 + acc1;
    }
    lds_barrier();

    // ---- PH_H: logits, argmax, logsumexp, state update (wave 0 only) ----
    if (tid < 64) {
      int s0 = lane, s1 = lane + 64;
      float l0 = (pu_l[s0] + pu_l[kS + s0]) + (pu_l[2*kS + s0] + pu_l[3*kS + s0]);
      float l1 = (pu_l[s1] + pu_l[kS + s1]) + (pu_l[2*kS + s1] + pu_l[3*kS + s1]);
      l0 += (mask_l[s0] > 0.f ? 0.f : -1e30f);
      l1 += (mask_l[s1] > 0.f ? 0.f : -1e30f);
      float es = __expf(l0) + __expf(l1);
      float mv; int mi;
      if (l1 > l0) { mv = l1; mi = s1; } else { mv = l0; mi = s0; }
#pragma unroll
      for (int off = 1; off < 64; off <<= 1) {
        float ov = __shfl_xor(mv, off);
        int oi = __shfl_xor(mi, off);
        if (ov > mv || (ov == mv && oi < mi)) { mv = ov; mi = oi; }
        es += __shfl_xor(es, off);
      }
      if (lane == 0) {
        out[b * kT + t] = (float)mi;
        out[kB * kT + b * kT + t] = mv - __logf(es);
        mask_l[mi] = 0.f;
        ptr_sh = mi;
      }
    }
    lds_barrier();
  }
}

}  // namespace

extern "C" void kernel_launch(void* const* d_in, const int* in_sizes, int n_in,
                              void* d_out, int out_size, void* d_ws, size_t ws_size,
                              hipStream_t stream) {
  const float* stat_g = (const float*)d_in[0];
  const float* dyn_g  = (const float*)d_in[1];
  const float* W_s   = (const float*)d_in[3];
  const float* b_s   = (const float*)d_in[4];
  const float* W_d   = (const float*)d_in[5];
  const float* b_d   = (const float*)d_in[6];
  const float* W_dec = (const float*)d_in[7];
  const float* b_dec = (const float*)d_in[8];
  const float* vv1   = (const float*)d_in[9];
  const float* ww1   = (const float*)d_in[10];
  const float* vv2   = (const float*)d_in[11];
  const float* ww2   = (const float*)d_in[12];
  const float* W_ih  = (const float*)d_in[13];
  const float* W_hh  = (const float*)d_in[14];
  const float* b_ih  = (const float*)d_in[15];
  const float* b_hh  = (const float*)d_in[16];

  float* ws = (float*)d_ws;
  float* out = (float*)d_out;

  prep_w<<<1, 256, 0, stream>>>(W_ih, W_dec, b_ih, b_dec, ww1, ww2, ws);
  prep_sh<<<kB, 256, 0, stream>>>(stat_g, dyn_g, W_s, b_s, W_d, b_d, ws);
  prep_base<<<dim3(kB, 2), 256, 0, stream>>>(ww1, ww2, ws);
  prep_gi<<<kB, 256, 0, stream>>>(stat_g, ws);
  ptrnet_main<<<kB, 512, 0, stream>>>(dyn_g, vv1, vv2, b_hh, W_hh, ws, out);
}

// Round 15
// 1344.573 us; speedup vs baseline: 1.5408x; 1.4153x over previous
//
#include <hip/hip_runtime.h>

// DRL4SSP pointer-network decoder, MI355X (gfx950).
// R9 chassis (best measured: 1151us) + gi_all table. 64 batches -> 64 blocks
// x 512 threads (allocator rule VGPR=65536/threads -> 128), 127 steps, 7
// __syncthreads/step. All weight streams read in-phase from L2 as dwordx4;
// gi for all 129 possible decoder inputs precomputed (3 loads/step instead of
// a Wcomb matvec); PH_H publishes argmax via ptr_sh.

namespace {

constexpr int kB = 64, kSS = 8, kDS = 4, kH = 128, kS = 128, kT = 127, kG3 = 384;

// workspace layout (float offsets)
constexpr size_t OFF_BASE1 = 0;
constexpr size_t OFF_BASE2 = OFF_BASE1 + (size_t)kB * kH * kS;
constexpr size_t OFF_SHT   = OFF_BASE2 + (size_t)kB * kH * kS;   // static_h^T [b][s][h]
constexpr size_t OFF_W1HT  = OFF_SHT   + (size_t)kB * kS * kH;   // [k][h]
constexpr size_t OFF_W2DT  = OFF_W1HT  + (size_t)kH * kH;
constexpr size_t OFF_WCT   = OFF_W2DT  + (size_t)kH * kH;        // WcombT [8][384]
constexpr size_t OFF_BCOMB = OFF_WCT   + (size_t)kSS * kG3;
constexpr size_t OFF_SHG   = OFF_BCOMB + kG3;                    // prep scratch
constexpr size_t OFF_DHG   = OFF_SHG   + (size_t)kB * kH * kS;   // prep scratch
constexpr size_t OFF_GIALL = OFF_SHG;                            // overlay: [b][129][384]

// static-LDS layout (float offsets)
constexpr int L_BASE1 = 0;        // 16384
constexpr int L_BASE2 = 16384;    // 16384
constexpr int L_BH    = 32768;    // 384
constexpr int L_PG    = 33152;    // 1536  [4 seg][3 gate][128]
constexpr int L_PU    = 34688;    // 512
constexpr int L_PA    = 35200;    // 512
constexpr int L_MASK  = 35712;    // 128
constexpr int L_WSUM  = 35840;    // 4
constexpr int L_RINV  = 35844;    // 1
constexpr int LDS_FLOATS = 35848; // 143,392 B

__device__ __forceinline__ float rlane(float v, int l) {
  return __uint_as_float(__builtin_amdgcn_readlane(__float_as_uint(v), (unsigned)l));
}

__device__ __forceinline__ float tanh_fast(float x) {
  // identical to rounds 1..14 (passing) — trajectory-sensitive
  x = fminf(15.f, fmaxf(-15.f, x));
  float e = __expf(-2.f * x);
  return (1.f - e) * __builtin_amdgcn_rcpf(1.f + e);
}

// ---------------- precompute kernels ----------------

__global__ void prep_w(const float* __restrict__ W_ih, const float* __restrict__ W_dec,
                       const float* __restrict__ b_ih, const float* __restrict__ b_dec,
                       const float* __restrict__ ww1, const float* __restrict__ ww2,
                       float* __restrict__ ws) {
  const int tid = threadIdx.x;
  float* WcT   = ws + OFF_WCT;
  float* bcomb = ws + OFF_BCOMB;
  float* w1hT  = ws + OFF_W1HT;
  float* w2dT  = ws + OFF_W2DT;
  for (int idx = tid; idx < kSS * kG3; idx += 256) {
    int i = idx / kG3, j = idx % kG3;
    float acc = 0.f;
    for (int k = 0; k < kH; ++k) acc = fmaf(W_ih[j * kH + k], W_dec[k * kSS + i], acc);
    WcT[idx] = acc;
  }
  for (int j = tid; j < kG3; j += 256) {
    float acc = b_ih[j];
    for (int k = 0; k < kH; ++k) acc = fmaf(W_ih[j * kH + k], b_dec[k], acc);
    bcomb[j] = acc;
  }
  for (int idx = tid; idx < kH * kH; idx += 256) {
    int k = idx >> 7, h = idx & 127;
    w1hT[idx] = ww1[h * kG3 + 2 * kH + k];
    w2dT[idx] = ww2[h * kG3 + kH + k];
  }
}

__global__ void prep_sh(const float* __restrict__ stat_g, const float* __restrict__ dyn_g,
                        const float* __restrict__ W_s, const float* __restrict__ b_s,
                        const float* __restrict__ W_d, const float* __restrict__ b_d,
                        float* __restrict__ ws) {
  const int b = blockIdx.x, tid = threadIdx.x;
  float* sh_g = ws + OFF_SHG;
  float* dh_g = ws + OFF_DHG;
  float* shT  = ws + OFF_SHT;
  const float* sb = stat_g + (size_t)b * kSS * kS;
  const float* db = dyn_g + (size_t)b * kDS * kS;
  for (int idx = tid; idx < kH * kS; idx += 256) {
    int k = idx >> 7, s = idx & 127;
    float acc = b_s[k];
#pragma unroll
    for (int i = 0; i < kSS; ++i) acc = fmaf(W_s[k * kSS + i], sb[i * kS + s], acc);
    sh_g[(size_t)b * kH * kS + idx] = acc;
    float accd = b_d[k];
#pragma unroll
    for (int i = 0; i < kDS; ++i) accd = fmaf(W_d[k * kDS + i], db[i * kS + s], accd);
    dh_g[(size_t)b * kH * kS + idx] = accd;
  }
  for (int idx = tid; idx < kS * kH; idx += 256) {
    int s = idx >> 7, k = idx & 127;
    float acc = b_s[k];
#pragma unroll
    for (int i = 0; i < kSS; ++i) acc = fmaf(W_s[k * kSS + i], sb[i * kS + s], acc);
    shT[(size_t)b * kS * kH + idx] = acc;
  }
}

__global__ void prep_base(const float* __restrict__ ww1, const float* __restrict__ ww2,
                          float* __restrict__ ws) {
  const int b = blockIdx.x, which = blockIdx.y, tid = threadIdx.x;
  const float* sh_g = ws + OFF_SHG + (size_t)b * kH * kS;
  const float* dh_g = ws + OFF_DHG + (size_t)b * kH * kS;
  const float* ww = which ? ww2 : ww1;
  const int dh_off = which ? 2 * kH : kH;
  float* dst = ws + (which ? OFF_BASE2 : OFF_BASE1) + (size_t)b * kH * kS;
  for (int idx = tid; idx < kH * kS / 4; idx += 256) {
    int h = idx >> 5, sq = idx & 31;
    const float* wrow = ww + h * kG3;
    float4 acc = make_float4(0.f, 0.f, 0.f, 0.f);
#pragma unroll 8
    for (int k = 0; k < kH; ++k) {
      float w = wrow[k];
      float4 v = *reinterpret_cast<const float4*>(sh_g + k * kS + sq * 4);
      acc.x = fmaf(w, v.x, acc.x); acc.y = fmaf(w, v.y, acc.y);
      acc.z = fmaf(w, v.z, acc.z); acc.w = fmaf(w, v.w, acc.w);
    }
#pragma unroll 8
    for (int k = 0; k < kH; ++k) {
      float w = wrow[dh_off + k];
      float4 v = *reinterpret_cast<const float4*>(dh_g + k * kS + sq * 4);
      acc.x = fmaf(w, v.x, acc.x); acc.y = fmaf(w, v.y, acc.y);
      acc.z = fmaf(w, v.z, acc.z); acc.w = fmaf(w, v.w, acc.w);
    }
    *reinterpret_cast<float4*>(dst + h * kS + sq * 4) = acc;
  }
}

// gi_all[b][s][j]; slot s=128 is the dec_in=0 case. Runs AFTER prep_base
// (overlays retired SHG/DHG scratch). Same fma order as the in-loop version,
// so gi values are bit-identical to rounds 1..14.
__global__ void prep_gi(const float* __restrict__ stat_g, float* __restrict__ ws) {
  const int b = blockIdx.x, tid = threadIdx.x;
  const float* WcT = ws + OFF_WCT;
  const float* bcomb = ws + OFF_BCOMB;
  float* gia = ws + OFF_GIALL + (size_t)b * (kS + 1) * kG3;
  const float* sb = stat_g + (size_t)b * kSS * kS;
  for (int idx = tid; idx < (kS + 1) * kG3; idx += 256) {
    int s = idx / kG3, j = idx % kG3;
    float acc = bcomb[j];
#pragma unroll
    for (int i = 0; i < kSS; ++i) {
      float d = (s < kS) ? sb[i * kS + s] : 0.f;
      acc = fmaf(WcT[i * kG3 + j], d, acc);
    }
    gia[idx] = acc;
  }
}

// ---------------- main sequential kernel ----------------

__global__ __launch_bounds__(512, 2) void ptrnet_main(
    const float* __restrict__ dyn_g,
    const float* __restrict__ vv1_g, const float* __restrict__ vv2_g,
    const float* __restrict__ bhh_g, const float* __restrict__ Whh_g,
    const float* __restrict__ ws, float* __restrict__ out) {
  __shared__ float sm[LDS_FLOATS];
  __shared__ int ptr_sh;
  const int b = blockIdx.x;
  const int tid = threadIdx.x;
  const int hh = tid & 127;
  const int seg = tid >> 7;            // 0..3
  const int lane = tid & 63;
  const int li = seg * 32 + (hh & 31);

  float* base1_l = sm + L_BASE1;
  float* base2_l = sm + L_BASE2;
  float* bh_l    = sm + L_BH;
  float* pg_l    = sm + L_PG;
  float* pu_l    = sm + L_PU;
  float* pa_l    = sm + L_PA;
  float* mask_l  = sm + L_MASK;
  float* wsum_l  = sm + L_WSUM;
  float* rinv_l  = sm + L_RINV;

  // ---- LDS init (one-time) ----
  {
    const float4* b1g = reinterpret_cast<const float4*>(ws + OFF_BASE1 + (size_t)b * kH * kS);
    const float4* b2g = reinterpret_cast<const float4*>(ws + OFF_BASE2 + (size_t)b * kH * kS);
    float4* b1l = reinterpret_cast<float4*>(base1_l);
    float4* b2l = reinterpret_cast<float4*>(base2_l);
    for (int i = tid; i < kH * kS / 4; i += 512) { b1l[i] = b1g[i]; b2l[i] = b2g[i]; }
    if (tid < kG3) bh_l[tid] = bhh_g[tid];
    if (tid < kS)
      mask_l[tid] = (tid == 0 || dyn_g[(size_t)b * kDS * kS + tid] != 0.f) ? 0.f : 1.f;
    if (tid == 0) ptr_sh = kS;   // slot 128 == dec_in = 0 (step 0)
  }

  const float v_vv1 = vv1_g[li], v_vv2 = vv2_g[li];
  float h_prev = 0.f;

  // stream bases (as R9)
  const float* whp0 = Whh_g + (size_t)(0 * kH + hh) * kH + seg * 32;  // gate r
  const float* whp1 = whp0 + (size_t)kH * kH;                         // gate z
  const float* whp2 = whp1 + (size_t)kH * kH;                         // gate n
  const float* w1p = ws + OFF_W1HT + (size_t)(seg * 32) * kH + hh;
  const float* w2p = ws + OFF_W2DT + (size_t)(seg * 32) * kH + hh;
  const float* shp = ws + OFF_SHT + (size_t)b * kS * kH + (size_t)(seg * 32) * kH + hh;
  const float* gia = ws + OFF_GIALL + (size_t)b * (kS + 1) * kG3;
  __syncthreads();

  for (int t = 0; t < kT; ++t) {
    // ---- PH_A: gi loads (consumed in PH_B) + gh partials (Whh streamed) ----
    float gi0, gi1, gi2;
    {
      const float* gp = gia + (size_t)ptr_sh * kG3 + li;
      gi0 = gp[0]; gi1 = gp[kH]; gi2 = gp[2 * kH];
      float4 q0[8], q1[8];
#pragma unroll
      for (int j = 0; j < 8; ++j) q0[j] = *reinterpret_cast<const float4*>(whp0 + 4 * j);
#pragma unroll
      for (int j = 0; j < 8; ++j) q1[j] = *reinterpret_cast<const float4*>(whp1 + 4 * j);
      float a0 = 0.f, a1 = 0.f;
#pragma unroll
      for (int j = 0; j < 8; ++j) {
        float4 w0 = q0[j], w1 = q1[j];
        float h0 = rlane(h_prev, 4 * j + 0), h1 = rlane(h_prev, 4 * j + 1);
        float h2 = rlane(h_prev, 4 * j + 2), h3 = rlane(h_prev, 4 * j + 3);
        a0 = fmaf(h0, w0.x, a0); a1 = fmaf(h0, w1.x, a1);
        a0 = fmaf(h1, w0.y, a0); a1 = fmaf(h1, w1.y, a1);
        a0 = fmaf(h2, w0.z, a0); a1 = fmaf(h2, w1.z, a1);
        a0 = fmaf(h3, w0.w, a0); a1 = fmaf(h3, w1.w, a1);
      }
#pragma unroll
      for (int j = 0; j < 8; ++j) q0[j] = *reinterpret_cast<const float4*>(whp2 + 4 * j);
      float a2x = 0.f, a2y = 0.f;
#pragma unroll
      for (int j = 0; j < 8; ++j) {
        float4 w = q0[j];
        a2x = fmaf(rlane(h_prev, 4 * j + 0), w.x, a2x);
        a2y = fmaf(rlane(h_prev, 4 * j + 1), w.y, a2y);
        a2x = fmaf(rlane(h_prev, 4 * j + 2), w.z, a2x);
        a2y = fmaf(rlane(h_prev, 4 * j + 3), w.w, a2y);
      }
      pg_l[(seg * 3 + 0) * kS + hh] = a0;
      pg_l[(seg * 3 + 1) * kS + hh] = a1;
      pg_l[(seg * 3 + 2) * kS + hh] = a2x + a2y;
    }
    __syncthreads();

    // ---- PH_B: GRU (replicated per-thread) + u1 partials (w1 streamed) ----
    {
      float b0[8], b1[8], b2[8], b3[8];
#pragma unroll
      for (int j = 0; j < 8; ++j) b0[j] = w1p[j * kH];
#pragma unroll
      for (int j = 0; j < 8; ++j) b1[j] = w1p[(8 + j) * kH];
#pragma unroll
      for (int j = 0; j < 8; ++j) b2[j] = w1p[(16 + j) * kH];
#pragma unroll
      for (int j = 0; j < 8; ++j) b3[j] = w1p[(24 + j) * kH];
      float gh0 = bh_l[li] +
          ((pg_l[(0*3+0)*kS+li] + pg_l[(1*3+0)*kS+li]) + (pg_l[(2*3+0)*kS+li] + pg_l[(3*3+0)*kS+li]));
      float gh1 = bh_l[kH + li] +
          ((pg_l[(0*3+1)*kS+li] + pg_l[(1*3+1)*kS+li]) + (pg_l[(2*3+1)*kS+li] + pg_l[(3*3+1)*kS+li]));
      float gh2 = bh_l[2*kH + li] +
          ((pg_l[(0*3+2)*kS+li] + pg_l[(1*3+2)*kS+li]) + (pg_l[(2*3+2)*kS+li] + pg_l[(3*3+2)*kS+li]));
      float r = 1.f / (1.f + __expf(-(gi0 + gh0)));
      float z = 1.f / (1.f + __expf(-(gi1 + gh1)));
      float x = gi2 + r * gh2;
      x = fminf(15.f, fmaxf(-15.f, x));
      float e = __expf(-2.f * x);
      float n = (1.f - e) / (1.f + e);
      float hnew = (1.f - z) * n + z * h_prev;
      h_prev = hnew;
      float acc0 = 0.f, acc1 = 0.f;
#pragma unroll
      for (int j = 0; j < 8; ++j) {
        acc0 = fmaf(rlane(hnew, j), b0[j], acc0);
        acc1 = fmaf(rlane(hnew, 8 + j), b1[j], acc1);
      }
#pragma unroll
      for (int j = 0; j < 8; ++j) {
        acc0 = fmaf(rlane(hnew, 16 + j), b2[j], acc0);
        acc1 = fmaf(rlane(hnew, 24 + j), b3[j], acc1);
      }
      pu_l[seg * kS + hh] = acc0 + acc1;
    }
    __syncthreads();

    // ---- PH_C: attn1 partials (tanh over 32 h-rows, base1 in LDS) ----
    {
      float v_u1 = (pu_l[li] + pu_l[kS + li]) + (pu_l[2*kS + li] + pu_l[3*kS + li]);
      float acc0 = 0.f, acc1 = 0.f;
#pragma unroll
      for (int kk = 0; kk < 16; ++kk) {
        float xa = base1_l[(seg * 32 + 2*kk) * kS + hh] + rlane(v_u1, 2*kk);
        float xb = base1_l[(seg * 32 + 2*kk+1) * kS + hh] + rlane(v_u1, 2*kk+1);
        acc0 = fmaf(rlane(v_vv1, 2*kk), tanh_fast(xa), acc0);
        acc1 = fmaf(rlane(v_vv1, 2*kk+1), tanh_fast(xb), acc1);
      }
      pa_l[seg * kS + hh] = acc0 + acc1;
    }
    __syncthreads();

    // ---- PH_E: softmax1 exp + chunk sums + dytext partials (sh streamed) ----
    {
      float b0[8], b1[8], b2[8], b3[8];
#pragma unroll
      for (int j = 0; j < 8; ++j) b0[j] = shp[j * kH];
#pragma unroll
      for (int j = 0; j < 8; ++j) b1[j] = shp[(8 + j) * kH];
#pragma unroll
      for (int j = 0; j < 8; ++j) b2[j] = shp[(16 + j) * kH];
#pragma unroll
      for (int j = 0; j < 8; ++j) b3[j] = shp[(24 + j) * kH];
      float a = (pa_l[li] + pa_l[kS + li]) + (pa_l[2*kS + li] + pa_l[3*kS + li]);
      float ee = __expf(fminf(a, 60.f));
      float ssum = ee;
#pragma unroll
      for (int off = 1; off < 32; off <<= 1) ssum += __shfl_xor(ssum, off);
      if ((lane & 31) == 0) wsum_l[seg] = ssum;
      float acc0 = 0.f, acc1 = 0.f;
#pragma unroll
      for (int j = 0; j < 8; ++j) {
        acc0 = fmaf(rlane(ee, j), b0[j], acc0);
        acc1 = fmaf(rlane(ee, 8 + j), b1[j], acc1);
      }
#pragma unroll
      for (int j = 0; j < 8; ++j) {
        acc0 = fmaf(rlane(ee, 16 + j), b2[j], acc0);
        acc1 = fmaf(rlane(ee, 24 + j), b3[j], acc1);
      }
      pu_l[seg * kS + hh] = acc0 + acc1;
    }
    __syncthreads();

    // ---- PH_F: u2 partials (w2 streamed); one thread computes 1/sum ----
    {
      float b0[8], b1[8], b2[8], b3[8];
#pragma unroll
      for (int j = 0; j < 8; ++j) b0[j] = w2p[j * kH];
#pragma unroll
      for (int j = 0; j < 8; ++j) b1[j] = w2p[(8 + j) * kH];
#pragma unroll
      for (int j = 0; j < 8; ++j) b2[j] = w2p[(16 + j) * kH];
#pragma unroll
      for (int j = 0; j < 8; ++j) b3[j] = w2p[(24 + j) * kH];
      float v_dy = (pu_l[li] + pu_l[kS + li]) + (pu_l[2*kS + li] + pu_l[3*kS + li]);
      float acc0 = 0.f, acc1 = 0.f;
#pragma unroll
      for (int j = 0; j < 8; ++j) {
        acc0 = fmaf(rlane(v_dy, j), b0[j], acc0);
        acc1 = fmaf(rlane(v_dy, 8 + j), b1[j], acc1);
      }
#pragma unroll
      for (int j = 0; j < 8; ++j) {
        acc0 = fmaf(rlane(v_dy, 16 + j), b2[j], acc0);
        acc1 = fmaf(rlane(v_dy, 24 + j), b3[j], acc1);
      }
      pa_l[seg * kS + hh] = acc0 + acc1;
      if (tid == 0) rinv_l[0] = 1.0f / ((wsum_l[0] + wsum_l[1]) + (wsum_l[2] + wsum_l[3]));
    }
    __syncthreads();

    // ---- PH_G: attn2 partials (tanh over 32 h-rows, base2 in LDS) ----
    {
      float rin = rinv_l[0];
      float v_u2 = ((pa_l[li] + pa_l[kS + li]) + (pa_l[2*kS + li] + pa_l[3*kS + li])) * rin;
      float acc0 = 0.f, acc1 = 0.f;
#pragma unroll
      for (int kk = 0; kk < 16; ++kk) {
        float xa = base2_l[(seg * 32 + 2*kk) * kS + hh] + rlane(v_u2, 2*kk);
        float xb = base2_l[(seg * 32 + 2*kk+1) * kS + hh] + rlane(v_u2, 2*kk+1);
        acc0 = fmaf(rlane(v_vv2, 2*kk), tanh_fast(xa), acc0);
        acc1 = fmaf(rlane(v_vv2, 2*kk+1), tanh_fast(xb), acc1);
      }
      pu_l[seg * kS + hh] = acc0 + acc1;
    }
    __syncthreads();

    // ---- PH_H: logits, argmax, logsumexp, state update (wave 0 only) ----
    if (tid < 64) {
      int s0 = lane, s1 = lane + 64;
      float l0 = (pu_l[s0] + pu_l[kS + s0]) + (pu_l[2*kS + s0] + pu_l[3*kS + s0]);
      float l1 = (pu_l[s1] + pu_l[kS + s1]) + (pu_l[2*kS + s1] + pu_l[3*kS + s1]);
      l0 += (mask_l[s0] > 0.f ? 0.f : -1e30f);
      l1 += (mask_l[s1] > 0.f ? 0.f : -1e30f);
      float es = __expf(l0) + __expf(l1);
      float mv; int mi;
      if (l1 > l0) { mv = l1; mi = s1; } else { mv = l0; mi = s0; }
#pragma unroll
      for (int off = 1; off < 64; off <<= 1) {
        float ov = __shfl_xor(mv, off);
        int oi = __shfl_xor(mi, off);
        if (ov > mv || (ov == mv && oi < mi)) { mv = ov; mi = oi; }
        es += __shfl_xor(es, off);
      }
      if (lane == 0) {
        out[b * kT + t] = (float)mi;
        out[kB * kT + b * kT + t] = mv - __logf(es);
        mask_l[mi] = 0.f;
        ptr_sh = mi;
      }
    }
    __syncthreads();
  }
}

}  // namespace

extern "C" void kernel_launch(void* const* d_in, const int* in_sizes, int n_in,
                              void* d_out, int out_size, void* d_ws, size_t ws_size,
                              hipStream_t stream) {
  const float* stat_g = (const float*)d_in[0];
  const float* dyn_g  = (const float*)d_in[1];
  const float* W_s   = (const float*)d_in[3];
  const float* b_s   = (const float*)d_in[4];
  const float* W_d   = (const float*)d_in[5];
  const float* b_d   = (const float*)d_in[6];
  const float* W_dec = (const float*)d_in[7];
  const float* b_dec = (const float*)d_in[8];
  const float* vv1   = (const float*)d_in[9];
  const float* ww1   = (const float*)d_in[10];
  const float* vv2   = (const float*)d_in[11];
  const float* ww2   = (const float*)d_in[12];
  const float* W_ih  = (const float*)d_in[13];
  const float* W_hh  = (const float*)d_in[14];
  const float* b_ih  = (const float*)d_in[15];
  const float* b_hh  = (const float*)d_in[16];

  float* ws = (float*)d_ws;
  float* out = (float*)d_out;

  prep_w<<<1, 256, 0, stream>>>(W_ih, W_dec, b_ih, b_dec, ww1, ww2, ws);
  prep_sh<<<kB, 256, 0, stream>>>(stat_g, dyn_g, W_s, b_s, W_d, b_d, ws);
  prep_base<<<dim3(kB, 2), 256, 0, stream>>>(ww1, ww2, ws);
  prep_gi<<<kB, 256, 0, stream>>>(stat_g, ws);
  ptrnet_main<<<kB, 512, 0, stream>>>(dyn_g, vv1, vv2, b_hh, W_hh, ws, out);
}

// Round 16
// 1233.750 us; speedup vs baseline: 1.6792x; 1.0898x over previous
//
#include <hip/hip_runtime.h>

// DRL4SSP pointer-network decoder, MI355X (gfx950).
// R15 chassis (best: 1030us) + M2 fusion (attn2's double matvec collapsed via
// precomputed M2[s][h] = sum_k w2d[h][k]*static_h[k][s]) + registerized mask
// with all-wave-redundant argmax. 64 blocks x 512 threads, 127 steps,
// 5 __syncthreads/step (was 7), one fewer matvec phase.

namespace {

constexpr int kB = 64, kSS = 8, kDS = 4, kH = 128, kS = 128, kT = 127, kG3 = 384;

// workspace layout (float offsets)
constexpr size_t OFF_BASE1 = 0;
constexpr size_t OFF_BASE2 = OFF_BASE1 + (size_t)kB * kH * kS;
constexpr size_t OFF_W1HT  = OFF_BASE2 + (size_t)kB * kH * kS;   // [k][h]
constexpr size_t OFF_W2DT  = OFF_W1HT  + (size_t)kH * kH;        // [k][h]
constexpr size_t OFF_WCT   = OFF_W2DT  + (size_t)kH * kH;        // WcombT [8][384]
constexpr size_t OFF_BCOMB = OFF_WCT   + (size_t)kSS * kG3;
constexpr size_t OFF_SHG   = OFF_BCOMB + kG3;                    // prep scratch [b][k][s]
constexpr size_t OFF_DHG   = OFF_SHG   + (size_t)kB * kH * kS;   // prep scratch
constexpr size_t OFF_GIALL = OFF_SHG;                            // overlay: [b][129][384]
constexpr size_t OFF_M2    = OFF_GIALL + (size_t)kB * (kS + 1) * kG3;  // [b][s][h]
// total = OFF_M2 + kB*kS*kH = ~6.35M floats (25.4 MB)

// static-LDS layout (float offsets)
constexpr int L_BASE1 = 0;        // 16384
constexpr int L_BASE2 = 16384;    // 16384
constexpr int L_BH    = 32768;    // 384
constexpr int L_PG    = 33152;    // 1536  [4 seg][3 gate][128]
constexpr int L_PU    = 34688;    // 512
constexpr int L_PA    = 35200;    // 512
constexpr int L_WSUM  = 35712;    // 4
constexpr int LDS_FLOATS = 35716; // 142,864 B

__device__ __forceinline__ float rlane(float v, int l) {
  return __uint_as_float(__builtin_amdgcn_readlane(__float_as_uint(v), (unsigned)l));
}

__device__ __forceinline__ float tanh_fast(float x) {
  // identical to rounds 1..15 (passing) — trajectory-sensitive
  x = fminf(15.f, fmaxf(-15.f, x));
  float e = __expf(-2.f * x);
  return (1.f - e) * __builtin_amdgcn_rcpf(1.f + e);
}

// ---------------- precompute kernels ----------------

__global__ void prep_w(const float* __restrict__ W_ih, const float* __restrict__ W_dec,
                       const float* __restrict__ b_ih, const float* __restrict__ b_dec,
                       const float* __restrict__ ww1, const float* __restrict__ ww2,
                       float* __restrict__ ws) {
  const int tid = threadIdx.x;
  float* WcT   = ws + OFF_WCT;
  float* bcomb = ws + OFF_BCOMB;
  float* w1hT  = ws + OFF_W1HT;
  float* w2dT  = ws + OFF_W2DT;
  for (int idx = tid; idx < kSS * kG3; idx += 256) {
    int i = idx / kG3, j = idx % kG3;
    float acc = 0.f;
    for (int k = 0; k < kH; ++k) acc = fmaf(W_ih[j * kH + k], W_dec[k * kSS + i], acc);
    WcT[idx] = acc;
  }
  for (int j = tid; j < kG3; j += 256) {
    float acc = b_ih[j];
    for (int k = 0; k < kH; ++k) acc = fmaf(W_ih[j * kH + k], b_dec[k], acc);
    bcomb[j] = acc;
  }
  for (int idx = tid; idx < kH * kH; idx += 256) {
    int k = idx >> 7, h = idx & 127;
    w1hT[idx] = ww1[h * kG3 + 2 * kH + k];
    w2dT[idx] = ww2[h * kG3 + kH + k];
  }
}

__global__ void prep_sh(const float* __restrict__ stat_g, const float* __restrict__ dyn_g,
                        const float* __restrict__ W_s, const float* __restrict__ b_s,
                        const float* __restrict__ W_d, const float* __restrict__ b_d,
                        float* __restrict__ ws) {
  const int b = blockIdx.x, tid = threadIdx.x;
  float* sh_g = ws + OFF_SHG;
  float* dh_g = ws + OFF_DHG;
  const float* sb = stat_g + (size_t)b * kSS * kS;
  const float* db = dyn_g + (size_t)b * kDS * kS;
  for (int idx = tid; idx < kH * kS; idx += 256) {
    int k = idx >> 7, s = idx & 127;
    float acc = b_s[k];
#pragma unroll
    for (int i = 0; i < kSS; ++i) acc = fmaf(W_s[k * kSS + i], sb[i * kS + s], acc);
    sh_g[(size_t)b * kH * kS + idx] = acc;
    float accd = b_d[k];
#pragma unroll
    for (int i = 0; i < kDS; ++i) accd = fmaf(W_d[k * kDS + i], db[i * kS + s], accd);
    dh_g[(size_t)b * kH * kS + idx] = accd;
  }
}

__global__ void prep_base(const float* __restrict__ ww1, const float* __restrict__ ww2,
                          float* __restrict__ ws) {
  const int b = blockIdx.x, which = blockIdx.y, tid = threadIdx.x;
  const float* sh_g = ws + OFF_SHG + (size_t)b * kH * kS;
  const float* dh_g = ws + OFF_DHG + (size_t)b * kH * kS;
  const float* ww = which ? ww2 : ww1;
  const int dh_off = which ? 2 * kH : kH;
  float* dst = ws + (which ? OFF_BASE2 : OFF_BASE1) + (size_t)b * kH * kS;
  for (int idx = tid; idx < kH * kS / 4; idx += 256) {
    int h = idx >> 5, sq = idx & 31;
    const float* wrow = ww + h * kG3;
    float4 acc = make_float4(0.f, 0.f, 0.f, 0.f);
#pragma unroll 8
    for (int k = 0; k < kH; ++k) {
      float w = wrow[k];
      float4 v = *reinterpret_cast<const float4*>(sh_g + k * kS + sq * 4);
      acc.x = fmaf(w, v.x, acc.x); acc.y = fmaf(w, v.y, acc.y);
      acc.z = fmaf(w, v.z, acc.z); acc.w = fmaf(w, v.w, acc.w);
    }
#pragma unroll 8
    for (int k = 0; k < kH; ++k) {
      float w = wrow[dh_off + k];
      float4 v = *reinterpret_cast<const float4*>(dh_g + k * kS + sq * 4);
      acc.x = fmaf(w, v.x, acc.x); acc.y = fmaf(w, v.y, acc.y);
      acc.z = fmaf(w, v.z, acc.z); acc.w = fmaf(w, v.w, acc.w);
    }
    *reinterpret_cast<float4*>(dst + h * kS + sq * 4) = acc;
  }
}

// M2[b][s][h] = sum_k w2d[h][k] * static_h[b][k][s]. Needs SHG scratch ->
// must run BEFORE prep_gi overwrites it.
__global__ void prep_m2(float* __restrict__ ws) {
  const int b = blockIdx.x, tid = threadIdx.x;
  const float* sh_g = ws + OFF_SHG + (size_t)b * kH * kS;  // [k][s]
  const float* w2dT = ws + OFF_W2DT;                        // [k][h]
  float* m2 = ws + OFF_M2 + (size_t)b * kS * kH;            // [s][h]
  for (int idx = tid; idx < kS * kH; idx += 256) {
    int s = idx >> 7, h = idx & 127;
    float acc = 0.f;
    for (int k = 0; k < kH; ++k)
      acc = fmaf(w2dT[k * kH + h], sh_g[k * kS + s], acc);
    m2[idx] = acc;
  }
}

// gi_all[b][s][j]; slot s=128 is the dec_in=0 case. Overlays SHG/DHG scratch.
__global__ void prep_gi(const float* __restrict__ stat_g, float* __restrict__ ws) {
  const int b = blockIdx.x, tid = threadIdx.x;
  const float* WcT = ws + OFF_WCT;
  const float* bcomb = ws + OFF_BCOMB;
  float* gia = ws + OFF_GIALL + (size_t)b * (kS + 1) * kG3;
  const float* sb = stat_g + (size_t)b * kSS * kS;
  for (int idx = tid; idx < (kS + 1) * kG3; idx += 256) {
    int s = idx / kG3, j = idx % kG3;
    float acc = bcomb[j];
#pragma unroll
    for (int i = 0; i < kSS; ++i) {
      float d = (s < kS) ? sb[i * kS + s] : 0.f;
      acc = fmaf(WcT[i * kG3 + j], d, acc);
    }
    gia[idx] = acc;
  }
}

// ---------------- main sequential kernel ----------------

__global__ __launch_bounds__(512, 2) void ptrnet_main(
    const float* __restrict__ dyn_g,
    const float* __restrict__ vv1_g, const float* __restrict__ vv2_g,
    const float* __restrict__ bhh_g, const float* __restrict__ Whh_g,
    const float* __restrict__ ws, float* __restrict__ out) {
  __shared__ float sm[LDS_FLOATS];
  const int b = blockIdx.x;
  const int tid = threadIdx.x;
  const int hh = tid & 127;
  const int seg = tid >> 7;            // 0..3
  const int lane = tid & 63;
  const int li = seg * 32 + (hh & 31);

  float* base1_l = sm + L_BASE1;
  float* base2_l = sm + L_BASE2;
  float* bh_l    = sm + L_BH;
  float* pg_l    = sm + L_PG;
  float* pu_l    = sm + L_PU;
  float* pa_l    = sm + L_PA;
  float* wsum_l  = sm + L_WSUM;

  // ---- LDS init (one-time) ----
  {
    const float4* b1g = reinterpret_cast<const float4*>(ws + OFF_BASE1 + (size_t)b * kH * kS);
    const float4* b2g = reinterpret_cast<const float4*>(ws + OFF_BASE2 + (size_t)b * kH * kS);
    float4* b1l = reinterpret_cast<float4*>(base1_l);
    float4* b2l = reinterpret_cast<float4*>(base2_l);
    for (int i = tid; i < kH * kS / 4; i += 512) { b1l[i] = b1g[i]; b2l[i] = b2g[i]; }
    if (tid < kG3) bh_l[tid] = bhh_g[tid];
  }

  // registerized mask bits for this thread's two s-values (same in all waves)
  float m0 = (lane == 0 || dyn_g[(size_t)b * kDS * kS + lane] != 0.f) ? 0.f : 1.f;
  float m1 = (dyn_g[(size_t)b * kDS * kS + lane + 64] != 0.f) ? 0.f : 1.f;
  int ptr_cur = kS;                    // slot 128 == dec_in = 0 (step 0)

  const float v_vv1 = vv1_g[li], v_vv2 = vv2_g[li];
  float h_prev = 0.f;

  // stream bases
  const float* whp0 = Whh_g + (size_t)(0 * kH + hh) * kH + seg * 32;  // gate r
  const float* whp1 = whp0 + (size_t)kH * kH;                         // gate z
  const float* whp2 = whp1 + (size_t)kH * kH;                         // gate n
  const float* w1p = ws + OFF_W1HT + (size_t)(seg * 32) * kH + hh;
  const float* m2p = ws + OFF_M2 + (size_t)b * kS * kH + (size_t)(seg * 32) * kH + hh;
  const float* gia = ws + OFF_GIALL + (size_t)b * (kS + 1) * kG3;
  __syncthreads();

  for (int t = 0; t < kT; ++t) {
    // ---- PH_A: gi loads (consumed in PH_B) + gh partials (Whh streamed) ----
    float gi0, gi1, gi2;
    {
      const float* gp = gia + (size_t)ptr_cur * kG3 + li;
      gi0 = gp[0]; gi1 = gp[kH]; gi2 = gp[2 * kH];
      float4 q0[8], q1[8];
#pragma unroll
      for (int j = 0; j < 8; ++j) q0[j] = *reinterpret_cast<const float4*>(whp0 + 4 * j);
#pragma unroll
      for (int j = 0; j < 8; ++j) q1[j] = *reinterpret_cast<const float4*>(whp1 + 4 * j);
      float a0 = 0.f, a1 = 0.f;
#pragma unroll
      for (int j = 0; j < 8; ++j) {
        float4 w0 = q0[j], w1 = q1[j];
        float h0 = rlane(h_prev, 4 * j + 0), h1 = rlane(h_prev, 4 * j + 1);
        float h2 = rlane(h_prev, 4 * j + 2), h3 = rlane(h_prev, 4 * j + 3);
        a0 = fmaf(h0, w0.x, a0); a1 = fmaf(h0, w1.x, a1);
        a0 = fmaf(h1, w0.y, a0); a1 = fmaf(h1, w1.y, a1);
        a0 = fmaf(h2, w0.z, a0); a1 = fmaf(h2, w1.z, a1);
        a0 = fmaf(h3, w0.w, a0); a1 = fmaf(h3, w1.w, a1);
      }
#pragma unroll
      for (int j = 0; j < 8; ++j) q0[j] = *reinterpret_cast<const float4*>(whp2 + 4 * j);
      float a2x = 0.f, a2y = 0.f;
#pragma unroll
      for (int j = 0; j < 8; ++j) {
        float4 w = q0[j];
        a2x = fmaf(rlane(h_prev, 4 * j + 0), w.x, a2x);
        a2y = fmaf(rlane(h_prev, 4 * j + 1), w.y, a2y);
        a2x = fmaf(rlane(h_prev, 4 * j + 2), w.z, a2x);
        a2y = fmaf(rlane(h_prev, 4 * j + 3), w.w, a2y);
      }
      pg_l[(seg * 3 + 0) * kS + hh] = a0;
      pg_l[(seg * 3 + 1) * kS + hh] = a1;
      pg_l[(seg * 3 + 2) * kS + hh] = a2x + a2y;
    }
    __syncthreads();

    // ---- PH_B: GRU (replicated per-thread) + u1 partials (w1 streamed) ----
    {
      float b0[8], b1[8], b2[8], b3[8];
#pragma unroll
      for (int j = 0; j < 8; ++j) b0[j] = w1p[j * kH];
#pragma unroll
      for (int j = 0; j < 8; ++j) b1[j] = w1p[(8 + j) * kH];
#pragma unroll
      for (int j = 0; j < 8; ++j) b2[j] = w1p[(16 + j) * kH];
#pragma unroll
      for (int j = 0; j < 8; ++j) b3[j] = w1p[(24 + j) * kH];
      float gh0 = bh_l[li] +
          ((pg_l[(0*3+0)*kS+li] + pg_l[(1*3+0)*kS+li]) + (pg_l[(2*3+0)*kS+li] + pg_l[(3*3+0)*kS+li]));
      float gh1 = bh_l[kH + li] +
          ((pg_l[(0*3+1)*kS+li] + pg_l[(1*3+1)*kS+li]) + (pg_l[(2*3+1)*kS+li] + pg_l[(3*3+1)*kS+li]));
      float gh2 = bh_l[2*kH + li] +
          ((pg_l[(0*3+2)*kS+li] + pg_l[(1*3+2)*kS+li]) + (pg_l[(2*3+2)*kS+li] + pg_l[(3*3+2)*kS+li]));
      float r = 1.f / (1.f + __expf(-(gi0 + gh0)));
      float z = 1.f / (1.f + __expf(-(gi1 + gh1)));
      float x = gi2 + r * gh2;
      x = fminf(15.f, fmaxf(-15.f, x));
      float e = __expf(-2.f * x);
      float n = (1.f - e) / (1.f + e);
      float hnew = (1.f - z) * n + z * h_prev;
      h_prev = hnew;
      float acc0 = 0.f, acc1 = 0.f;
#pragma unroll
      for (int j = 0; j < 8; ++j) {
        acc0 = fmaf(rlane(hnew, j), b0[j], acc0);
        acc1 = fmaf(rlane(hnew, 8 + j), b1[j], acc1);
      }
#pragma unroll
      for (int j = 0; j < 8; ++j) {
        acc0 = fmaf(rlane(hnew, 16 + j), b2[j], acc0);
        acc1 = fmaf(rlane(hnew, 24 + j), b3[j], acc1);
      }
      pu_l[seg * kS + hh] = acc0 + acc1;
    }
    __syncthreads();

    // ---- PH_C: attn1 partials (tanh over 32 h-rows, base1 in LDS) ----
    {
      float v_u1 = (pu_l[li] + pu_l[kS + li]) + (pu_l[2*kS + li] + pu_l[3*kS + li]);
      float acc0 = 0.f, acc1 = 0.f;
#pragma unroll
      for (int kk = 0; kk < 16; ++kk) {
        float xa = base1_l[(seg * 32 + 2*kk) * kS + hh] + rlane(v_u1, 2*kk);
        float xb = base1_l[(seg * 32 + 2*kk+1) * kS + hh] + rlane(v_u1, 2*kk+1);
        acc0 = fmaf(rlane(v_vv1, 2*kk), tanh_fast(xa), acc0);
        acc1 = fmaf(rlane(v_vv1, 2*kk+1), tanh_fast(xb), acc1);
      }
      pa_l[seg * kS + hh] = acc0 + acc1;
    }
    __syncthreads();

    // ---- PH_E: softmax1 exp + chunk sums + u2raw partials (M2 streamed) ----
    {
      float b0[8], b1[8], b2[8], b3[8];
#pragma unroll
      for (int j = 0; j < 8; ++j) b0[j] = m2p[j * kH];
#pragma unroll
      for (int j = 0; j < 8; ++j) b1[j] = m2p[(8 + j) * kH];
#pragma unroll
      for (int j = 0; j < 8; ++j) b2[j] = m2p[(16 + j) * kH];
#pragma unroll
      for (int j = 0; j < 8; ++j) b3[j] = m2p[(24 + j) * kH];
      float a = (pa_l[li] + pa_l[kS + li]) + (pa_l[2*kS + li] + pa_l[3*kS + li]);
      float ee = __expf(fminf(a, 60.f));
      float ssum = ee;
#pragma unroll
      for (int off = 1; off < 32; off <<= 1) ssum += __shfl_xor(ssum, off);
      if ((lane & 31) == 0) wsum_l[seg] = ssum;
      float acc0 = 0.f, acc1 = 0.f;
#pragma unroll
      for (int j = 0; j < 8; ++j) {
        acc0 = fmaf(rlane(ee, j), b0[j], acc0);
        acc1 = fmaf(rlane(ee, 8 + j), b1[j], acc1);
      }
#pragma unroll
      for (int j = 0; j < 8; ++j) {
        acc0 = fmaf(rlane(ee, 16 + j), b2[j], acc0);
        acc1 = fmaf(rlane(ee, 24 + j), b3[j], acc1);
      }
      pu_l[seg * kS + hh] = acc0 + acc1;   // u2raw partials
    }
    __syncthreads();

    // ---- PH_G: attn2 partials (tanh over 32 h-rows, base2 in LDS) ----
    {
      float rin = 1.0f / ((wsum_l[0] + wsum_l[1]) + (wsum_l[2] + wsum_l[3]));
      float v_u2 = ((pu_l[li] + pu_l[kS + li]) + (pu_l[2*kS + li] + pu_l[3*kS + li])) * rin;
      float acc0 = 0.f, acc1 = 0.f;
#pragma unroll
      for (int kk = 0; kk < 16; ++kk) {
        float xa = base2_l[(seg * 32 + 2*kk) * kS + hh] + rlane(v_u2, 2*kk);
        float xb = base2_l[(seg * 32 + 2*kk+1) * kS + hh] + rlane(v_u2, 2*kk+1);
        acc0 = fmaf(rlane(v_vv2, 2*kk), tanh_fast(xa), acc0);
        acc1 = fmaf(rlane(v_vv2, 2*kk+1), tanh_fast(xb), acc1);
      }
      pa_l[seg * kS + hh] = acc0 + acc1;
    }
    __syncthreads();

    // ---- PH_H: logits + argmax (all waves redundantly, register mask) ----
    {
      int s0 = lane, s1 = lane + 64;
      float l0 = (pa_l[s0] + pa_l[kS + s0]) + (pa_l[2*kS + s0] + pa_l[3*kS + s0]);
      float l1 = (pa_l[s1] + pa_l[kS + s1]) + (pa_l[2*kS + s1] + pa_l[3*kS + s1]);
      l0 += (m0 > 0.f ? 0.f : -1e30f);
      l1 += (m1 > 0.f ? 0.f : -1e30f);
      float es = __expf(l0) + __expf(l1);
      float mv; int mi;
      if (l1 > l0) { mv = l1; mi = s1; } else { mv = l0; mi = s0; }
#pragma unroll
      for (int off = 1; off < 64; off <<= 1) {
        float ov = __shfl_xor(mv, off);
        int oi = __shfl_xor(mi, off);
        if (ov > mv || (ov == mv && oi < mi)) { mv = ov; mi = oi; }
        es += __shfl_xor(es, off);
      }
      if (tid == 0) {
        out[b * kT + t] = (float)mi;
        out[kB * kT + b * kT + t] = mv - __logf(es);
      }
      if (mi == s0) m0 = 0.f;
      if (mi == s1) m1 = 0.f;
      ptr_cur = mi;
    }
    // no barrier: PH_A only writes pg_l (not touched by PH_H); pa_l is next
    // written in PH_C, two barriers away.
  }
}

}  // namespace

extern "C" void kernel_launch(void* const* d_in, const int* in_sizes, int n_in,
                              void* d_out, int out_size, void* d_ws, size_t ws_size,
                              hipStream_t stream) {
  const float* stat_g = (const float*)d_in[0];
  const float* dyn_g  = (const float*)d_in[1];
  const float* W_s   = (const float*)d_in[3];
  const float* b_s   = (const float*)d_in[4];
  const float* W_d   = (const float*)d_in[5];
  const float* b_d   = (const float*)d_in[6];
  const float* W_dec = (const float*)d_in[7];
  const float* b_dec = (const float*)d_in[8];
  const float* vv1   = (const float*)d_in[9];
  const float* ww1   = (const float*)d_in[10];
  const float* vv2   = (const float*)d_in[11];
  const float* ww2   = (const float*)d_in[12];
  const float* W_ih  = (const float*)d_in[13];
  const float* W_hh  = (const float*)d_in[14];
  const float* b_ih  = (const float*)d_in[15];
  const float* b_hh  = (const float*)d_in[16];

  float* ws = (float*)d_ws;
  float* out = (float*)d_out;

  prep_w<<<1, 256, 0, stream>>>(W_ih, W_dec, b_ih, b_dec, ww1, ww2, ws);
  prep_sh<<<kB, 256, 0, stream>>>(stat_g, dyn_g, W_s, b_s, W_d, b_d, ws);
  prep_base<<<dim3(kB, 2), 256, 0, stream>>>(ww1, ww2, ws);
  prep_m2<<<kB, 256, 0, stream>>>(ws);          // uses SHG scratch
  prep_gi<<<kB, 256, 0, stream>>>(stat_g, ws);  // overlays SHG/DHG after m2
  ptrnet_main<<<kB, 512, 0, stream>>>(dyn_g, vv1, vv2, b_hh, W_hh, ws, out);
}

// Round 19
// 1179.363 us; speedup vs baseline: 1.7566x; 1.0461x over previous
//
#include <hip/hip_runtime.h>

// DRL4SSP pointer-network decoder, MI355X (gfx950).
// R16 chassis (761us) + fast attention-tanh: vv*tanh(x) = vv - 2vv/(e^{2x}+1),
// with 2*base1/2*base2 pre-scaled in LDS and per-seg vvsum precomputed.
// 64 blocks x 512 threads, 127 steps, 5 barriers/step, zero spill.

namespace {

constexpr int kB = 64, kSS = 8, kDS = 4, kH = 128, kS = 128, kT = 127, kG3 = 384;

// workspace layout (float offsets)
constexpr size_t OFF_BASE1 = 0;
constexpr size_t OFF_BASE2 = OFF_BASE1 + (size_t)kB * kH * kS;
constexpr size_t OFF_W1HT  = OFF_BASE2 + (size_t)kB * kH * kS;   // [k][h]
constexpr size_t OFF_W2DT  = OFF_W1HT  + (size_t)kH * kH;        // [k][h]
constexpr size_t OFF_WCT   = OFF_W2DT  + (size_t)kH * kH;        // WcombT [8][384]
constexpr size_t OFF_BCOMB = OFF_WCT   + (size_t)kSS * kG3;
constexpr size_t OFF_SHG   = OFF_BCOMB + kG3;                    // prep scratch [b][k][s]
constexpr size_t OFF_DHG   = OFF_SHG   + (size_t)kB * kH * kS;   // prep scratch
constexpr size_t OFF_GIALL = OFF_SHG;                            // overlay: [b][129][384]
constexpr size_t OFF_M2    = OFF_GIALL + (size_t)kB * (kS + 1) * kG3;  // [b][s][h]

// static-LDS layout (float offsets)
constexpr int L_BASE1 = 0;        // 16384 (holds 2*base1)
constexpr int L_BASE2 = 16384;    // 16384 (holds 2*base2)
constexpr int L_BH    = 32768;    // 384
constexpr int L_PG    = 33152;    // 1536  [4 seg][3 gate][128]
constexpr int L_PU    = 34688;    // 512
constexpr int L_PA    = 35200;    // 512
constexpr int L_WSUM  = 35712;    // 4
constexpr int LDS_FLOATS = 35716; // 142,864 B

__device__ __forceinline__ float rlane(float v, int l) {
  return __uint_as_float(__builtin_amdgcn_readlane(__float_as_uint(v), (unsigned)l));
}

__device__ __forceinline__ float tanh_fast(float x) {
  // identical to rounds 1..16 — used by the GRU n-gate only (trajectory-critical)
  x = fminf(15.f, fmaxf(-15.f, x));
  float e = __expf(-2.f * x);
  return (1.f - e) * __builtin_amdgcn_rcpf(1.f + e);
}

// ---------------- precompute kernels ----------------

__global__ void prep_w(const float* __restrict__ W_ih, const float* __restrict__ W_dec,
                       const float* __restrict__ b_ih, const float* __restrict__ b_dec,
                       const float* __restrict__ ww1, const float* __restrict__ ww2,
                       float* __restrict__ ws) {
  const int tid = threadIdx.x;
  float* WcT   = ws + OFF_WCT;
  float* bcomb = ws + OFF_BCOMB;
  float* w1hT  = ws + OFF_W1HT;
  float* w2dT  = ws + OFF_W2DT;
  for (int idx = tid; idx < kSS * kG3; idx += 256) {
    int i = idx / kG3, j = idx % kG3;
    float acc = 0.f;
    for (int k = 0; k < kH; ++k) acc = fmaf(W_ih[j * kH + k], W_dec[k * kSS + i], acc);
    WcT[idx] = acc;
  }
  for (int j = tid; j < kG3; j += 256) {
    float acc = b_ih[j];
    for (int k = 0; k < kH; ++k) acc = fmaf(W_ih[j * kH + k], b_dec[k], acc);
    bcomb[j] = acc;
  }
  for (int idx = tid; idx < kH * kH; idx += 256) {
    int k = idx >> 7, h = idx & 127;
    w1hT[idx] = ww1[h * kG3 + 2 * kH + k];
    w2dT[idx] = ww2[h * kG3 + kH + k];
  }
}

__global__ void prep_sh(const float* __restrict__ stat_g, const float* __restrict__ dyn_g,
                        const float* __restrict__ W_s, const float* __restrict__ b_s,
                        const float* __restrict__ W_d, const float* __restrict__ b_d,
                        float* __restrict__ ws) {
  const int b = blockIdx.x, tid = threadIdx.x;
  float* sh_g = ws + OFF_SHG;
  float* dh_g = ws + OFF_DHG;
  const float* sb = stat_g + (size_t)b * kSS * kS;
  const float* db = dyn_g + (size_t)b * kDS * kS;
  for (int idx = tid; idx < kH * kS; idx += 256) {
    int k = idx >> 7, s = idx & 127;
    float acc = b_s[k];
#pragma unroll
    for (int i = 0; i < kSS; ++i) acc = fmaf(W_s[k * kSS + i], sb[i * kS + s], acc);
    sh_g[(size_t)b * kH * kS + idx] = acc;
    float accd = b_d[k];
#pragma unroll
    for (int i = 0; i < kDS; ++i) accd = fmaf(W_d[k * kDS + i], db[i * kS + s], accd);
    dh_g[(size_t)b * kH * kS + idx] = accd;
  }
}

__global__ void prep_base(const float* __restrict__ ww1, const float* __restrict__ ww2,
                          float* __restrict__ ws) {
  const int b = blockIdx.x, which = blockIdx.y, tid = threadIdx.x;
  const float* sh_g = ws + OFF_SHG + (size_t)b * kH * kS;
  const float* dh_g = ws + OFF_DHG + (size_t)b * kH * kS;
  const float* ww = which ? ww2 : ww1;
  const int dh_off = which ? 2 * kH : kH;
  float* dst = ws + (which ? OFF_BASE2 : OFF_BASE1) + (size_t)b * kH * kS;
  for (int idx = tid; idx < kH * kS / 4; idx += 256) {
    int h = idx >> 5, sq = idx & 31;
    const float* wrow = ww + h * kG3;
    float4 acc = make_float4(0.f, 0.f, 0.f, 0.f);
#pragma unroll 8
    for (int k = 0; k < kH; ++k) {
      float w = wrow[k];
      float4 v = *reinterpret_cast<const float4*>(sh_g + k * kS + sq * 4);
      acc.x = fmaf(w, v.x, acc.x); acc.y = fmaf(w, v.y, acc.y);
      acc.z = fmaf(w, v.z, acc.z); acc.w = fmaf(w, v.w, acc.w);
    }
#pragma unroll 8
    for (int k = 0; k < kH; ++k) {
      float w = wrow[dh_off + k];
      float4 v = *reinterpret_cast<const float4*>(dh_g + k * kS + sq * 4);
      acc.x = fmaf(w, v.x, acc.x); acc.y = fmaf(w, v.y, acc.y);
      acc.z = fmaf(w, v.z, acc.z); acc.w = fmaf(w, v.w, acc.w);
    }
    *reinterpret_cast<float4*>(dst + h * kS + sq * 4) = acc;
  }
}

// M2[b][s][h] = sum_k w2d[h][k] * static_h[b][k][s] (needs SHG; runs pre-gi)
__global__ void prep_m2(float* __restrict__ ws) {
  const int b = blockIdx.x, tid = threadIdx.x;
  const float* sh_g = ws + OFF_SHG + (size_t)b * kH * kS;
  const float* w2dT = ws + OFF_W2DT;
  float* m2 = ws + OFF_M2 + (size_t)b * kS * kH;
  for (int idx = tid; idx < kS * kH; idx += 256) {
    int s = idx >> 7, h = idx & 127;
    float acc = 0.f;
    for (int k = 0; k < kH; ++k)
      acc = fmaf(w2dT[k * kH + h], sh_g[k * kS + s], acc);
    m2[idx] = acc;
  }
}

// gi_all[b][s][j]; slot s=128 is the dec_in=0 case. Overlays SHG/DHG scratch.
__global__ void prep_gi(const float* __restrict__ stat_g, float* __restrict__ ws) {
  const int b = blockIdx.x, tid = threadIdx.x;
  const float* WcT = ws + OFF_WCT;
  const float* bcomb = ws + OFF_BCOMB;
  float* gia = ws + OFF_GIALL + (size_t)b * (kS + 1) * kG3;
  const float* sb = stat_g + (size_t)b * kSS * kS;
  for (int idx = tid; idx < (kS + 1) * kG3; idx += 256) {
    int s = idx / kG3, j = idx % kG3;
    float acc = bcomb[j];
#pragma unroll
    for (int i = 0; i < kSS; ++i) {
      float d = (s < kS) ? sb[i * kS + s] : 0.f;
      acc = fmaf(WcT[i * kG3 + j], d, acc);
    }
    gia[idx] = acc;
  }
}

// ---------------- main sequential kernel ----------------

__global__ __launch_bounds__(512, 2) void ptrnet_main(
    const float* __restrict__ dyn_g,
    const float* __restrict__ vv1_g, const float* __restrict__ vv2_g,
    const float* __restrict__ bhh_g, const float* __restrict__ Whh_g,
    const float* __restrict__ ws, float* __restrict__ out) {
  __shared__ float sm[LDS_FLOATS];
  const int b = blockIdx.x;
  const int tid = threadIdx.x;
  const int hh = tid & 127;
  const int seg = tid >> 7;            // 0..3
  const int lane = tid & 63;
  const int li = seg * 32 + (hh & 31);

  float* base1_l = sm + L_BASE1;   // 2*base1
  float* base2_l = sm + L_BASE2;   // 2*base2
  float* bh_l    = sm + L_BH;
  float* pg_l    = sm + L_PG;
  float* pu_l    = sm + L_PU;
  float* pa_l    = sm + L_PA;
  float* wsum_l  = sm + L_WSUM;

  // ---- LDS init (one-time): copy bases scaled by 2 ----
  {
    const float4* b1g = reinterpret_cast<const float4*>(ws + OFF_BASE1 + (size_t)b * kH * kS);
    const float4* b2g = reinterpret_cast<const float4*>(ws + OFF_BASE2 + (size_t)b * kH * kS);
    float4* b1l = reinterpret_cast<float4*>(base1_l);
    float4* b2l = reinterpret_cast<float4*>(base2_l);
    for (int i = tid; i < kH * kS / 4; i += 512) {
      float4 v1 = b1g[i], v2 = b2g[i];
      v1.x += v1.x; v1.y += v1.y; v1.z += v1.z; v1.w += v1.w;
      v2.x += v2.x; v2.y += v2.y; v2.z += v2.z; v2.w += v2.w;
      b1l[i] = v1; b2l[i] = v2;
    }
    if (tid < kG3) bh_l[tid] = bhh_g[tid];
  }

  // registerized mask bits for this thread's two s-values (same in all waves)
  float m0 = (lane == 0 || dyn_g[(size_t)b * kDS * kS + lane] != 0.f) ? 0.f : 1.f;
  float m1 = (dyn_g[(size_t)b * kDS * kS + lane + 64] != 0.f) ? 0.f : 1.f;
  int ptr_cur = kS;                    // slot 128 == dec_in = 0 (step 0)

  const float v_vv1 = vv1_g[li], v_vv2 = vv2_g[li];
  // per-seg vv sums (step-invariant; new math, order-free)
  float vvsum1 = 0.f, vvsum2 = 0.f;
#pragma unroll
  for (int kk = 0; kk < 32; ++kk) {
    vvsum1 += rlane(v_vv1, kk);
    vvsum2 += rlane(v_vv2, kk);
  }
  float h_prev = 0.f;

  // stream bases
  const float* whp0 = Whh_g + (size_t)(0 * kH + hh) * kH + seg * 32;  // gate r
  const float* whp1 = whp0 + (size_t)kH * kH;                         // gate z
  const float* whp2 = whp1 + (size_t)kH * kH;                         // gate n
  const float* w1p = ws + OFF_W1HT + (size_t)(seg * 32) * kH + hh;
  const float* m2p = ws + OFF_M2 + (size_t)b * kS * kH + (size_t)(seg * 32) * kH + hh;
  const float* gia = ws + OFF_GIALL + (size_t)b * (kS + 1) * kG3;
  __syncthreads();

  for (int t = 0; t < kT; ++t) {
    // ---- PH_A: gi loads (consumed in PH_B) + gh partials (Whh streamed) ----
    float gi0, gi1, gi2;
    {
      const float* gp = gia + (size_t)ptr_cur * kG3 + li;
      gi0 = gp[0]; gi1 = gp[kH]; gi2 = gp[2 * kH];
      float4 q0[8], q1[8];
#pragma unroll
      for (int j = 0; j < 8; ++j) q0[j] = *reinterpret_cast<const float4*>(whp0 + 4 * j);
#pragma unroll
      for (int j = 0; j < 8; ++j) q1[j] = *reinterpret_cast<const float4*>(whp1 + 4 * j);
      float a0 = 0.f, a1 = 0.f;
#pragma unroll
      for (int j = 0; j < 8; ++j) {
        float4 w0 = q0[j], w1 = q1[j];
        float h0 = rlane(h_prev, 4 * j + 0), h1 = rlane(h_prev, 4 * j + 1);
        float h2 = rlane(h_prev, 4 * j + 2), h3 = rlane(h_prev, 4 * j + 3);
        a0 = fmaf(h0, w0.x, a0); a1 = fmaf(h0, w1.x, a1);
        a0 = fmaf(h1, w0.y, a0); a1 = fmaf(h1, w1.y, a1);
        a0 = fmaf(h2, w0.z, a0); a1 = fmaf(h2, w1.z, a1);
        a0 = fmaf(h3, w0.w, a0); a1 = fmaf(h3, w1.w, a1);
      }
#pragma unroll
      for (int j = 0; j < 8; ++j) q0[j] = *reinterpret_cast<const float4*>(whp2 + 4 * j);
      float a2x = 0.f, a2y = 0.f;
#pragma unroll
      for (int j = 0; j < 8; ++j) {
        float4 w = q0[j];
        a2x = fmaf(rlane(h_prev, 4 * j + 0), w.x, a2x);
        a2y = fmaf(rlane(h_prev, 4 * j + 1), w.y, a2y);
        a2x = fmaf(rlane(h_prev, 4 * j + 2), w.z, a2x);
        a2y = fmaf(rlane(h_prev, 4 * j + 3), w.w, a2y);
      }
      pg_l[(seg * 3 + 0) * kS + hh] = a0;
      pg_l[(seg * 3 + 1) * kS + hh] = a1;
      pg_l[(seg * 3 + 2) * kS + hh] = a2x + a2y;
    }
    __syncthreads();

    // ---- PH_B: GRU (replicated per-thread) + u1 partials (w1 streamed) ----
    {
      float b0[8], b1[8], b2[8], b3[8];
#pragma unroll
      for (int j = 0; j < 8; ++j) b0[j] = w1p[j * kH];
#pragma unroll
      for (int j = 0; j < 8; ++j) b1[j] = w1p[(8 + j) * kH];
#pragma unroll
      for (int j = 0; j < 8; ++j) b2[j] = w1p[(16 + j) * kH];
#pragma unroll
      for (int j = 0; j < 8; ++j) b3[j] = w1p[(24 + j) * kH];
      float gh0 = bh_l[li] +
          ((pg_l[(0*3+0)*kS+li] + pg_l[(1*3+0)*kS+li]) + (pg_l[(2*3+0)*kS+li] + pg_l[(3*3+0)*kS+li]));
      float gh1 = bh_l[kH + li] +
          ((pg_l[(0*3+1)*kS+li] + pg_l[(1*3+1)*kS+li]) + (pg_l[(2*3+1)*kS+li] + pg_l[(3*3+1)*kS+li]));
      float gh2 = bh_l[2*kH + li] +
          ((pg_l[(0*3+2)*kS+li] + pg_l[(1*3+2)*kS+li]) + (pg_l[(2*3+2)*kS+li] + pg_l[(3*3+2)*kS+li]));
      float r = 1.f / (1.f + __expf(-(gi0 + gh0)));
      float z = 1.f / (1.f + __expf(-(gi1 + gh1)));
      float x = gi2 + r * gh2;
      x = fminf(15.f, fmaxf(-15.f, x));
      float e = __expf(-2.f * x);
      float n = (1.f - e) / (1.f + e);
      float hnew = (1.f - z) * n + z * h_prev;
      h_prev = hnew;
      float acc0 = 0.f, acc1 = 0.f;
#pragma unroll
      for (int j = 0; j < 8; ++j) {
        acc0 = fmaf(rlane(hnew, j), b0[j], acc0);
        acc1 = fmaf(rlane(hnew, 8 + j), b1[j], acc1);
      }
#pragma unroll
      for (int j = 0; j < 8; ++j) {
        acc0 = fmaf(rlane(hnew, 16 + j), b2[j], acc0);
        acc1 = fmaf(rlane(hnew, 24 + j), b3[j], acc1);
      }
      pu_l[seg * kS + hh] = acc0 + acc1;
    }
    __syncthreads();

    // ---- PH_C: attn1 partials via vv - 2vv/(e^{2x}+1)  (2*base1 in LDS) ----
    {
      float v_u1 = (pu_l[li] + pu_l[kS + li]) + (pu_l[2*kS + li] + pu_l[3*kS + li]);
      float u2x = v_u1 + v_u1;
      float acc0 = 0.f, acc1 = 0.f;
#pragma unroll
      for (int kk = 0; kk < 16; ++kk) {
        float xa = base1_l[(seg * 32 + 2*kk) * kS + hh] + rlane(u2x, 2*kk);
        float xb = base1_l[(seg * 32 + 2*kk+1) * kS + hh] + rlane(u2x, 2*kk+1);
        float ra = __builtin_amdgcn_rcpf(__expf(xa) + 1.f);
        float rb = __builtin_amdgcn_rcpf(__expf(xb) + 1.f);
        acc0 = fmaf(rlane(v_vv1, 2*kk), ra, acc0);
        acc1 = fmaf(rlane(v_vv1, 2*kk+1), rb, acc1);
      }
      pa_l[seg * kS + hh] = vvsum1 - 2.f * (acc0 + acc1);
    }
    __syncthreads();

    // ---- PH_E: softmax1 exp + chunk sums + u2raw partials (M2 streamed) ----
    {
      float b0[8], b1[8], b2[8], b3[8];
#pragma unroll
      for (int j = 0; j < 8; ++j) b0[j] = m2p[j * kH];
#pragma unroll
      for (int j = 0; j < 8; ++j) b1[j] = m2p[(8 + j) * kH];
#pragma unroll
      for (int j = 0; j < 8; ++j) b2[j] = m2p[(16 + j) * kH];
#pragma unroll
      for (int j = 0; j < 8; ++j) b3[j] = m2p[(24 + j) * kH];
      float a = (pa_l[li] + pa_l[kS + li]) + (pa_l[2*kS + li] + pa_l[3*kS + li]);
      float ee = __expf(fminf(a, 60.f));
      float ssum = ee;
#pragma unroll
      for (int off = 1; off < 32; off <<= 1) ssum += __shfl_xor(ssum, off);
      if ((lane & 31) == 0) wsum_l[seg] = ssum;
      float acc0 = 0.f, acc1 = 0.f;
#pragma unroll
      for (int j = 0; j < 8; ++j) {
        acc0 = fmaf(rlane(ee, j), b0[j], acc0);
        acc1 = fmaf(rlane(ee, 8 + j), b1[j], acc1);
      }
#pragma unroll
      for (int j = 0; j < 8; ++j) {
        acc0 = fmaf(rlane(ee, 16 + j), b2[j], acc0);
        acc1 = fmaf(rlane(ee, 24 + j), b3[j], acc1);
      }
      pu_l[seg * kS + hh] = acc0 + acc1;   // u2raw partials
    }
    __syncthreads();

    // ---- PH_G: attn2 partials via vv - 2vv/(e^{2x}+1)  (2*base2 in LDS) ----
    {
      float rin2 = 2.0f / ((wsum_l[0] + wsum_l[1]) + (wsum_l[2] + wsum_l[3]));
      float v_u2x = ((pu_l[li] + pu_l[kS + li]) + (pu_l[2*kS + li] + pu_l[3*kS + li])) * rin2;
      float acc0 = 0.f, acc1 = 0.f;
#pragma unroll
      for (int kk = 0; kk < 16; ++kk) {
        float xa = base2_l[(seg * 32 + 2*kk) * kS + hh] + rlane(v_u2x, 2*kk);
        float xb = base2_l[(seg * 32 + 2*kk+1) * kS + hh] + rlane(v_u2x, 2*kk+1);
        float ra = __builtin_amdgcn_rcpf(__expf(xa) + 1.f);
        float rb = __builtin_amdgcn_rcpf(__expf(xb) + 1.f);
        acc0 = fmaf(rlane(v_vv2, 2*kk), ra, acc0);
        acc1 = fmaf(rlane(v_vv2, 2*kk+1), rb, acc1);
      }
      pa_l[seg * kS + hh] = vvsum2 - 2.f * (acc0 + acc1);
    }
    __syncthreads();

    // ---- PH_H: logits + argmax (all waves redundantly, register mask) ----
    {
      int s0 = lane, s1 = lane + 64;
      float l0 = (pa_l[s0] + pa_l[kS + s0]) + (pa_l[2*kS + s0] + pa_l[3*kS + s0]);
      float l1 = (pa_l[s1] + pa_l[kS + s1]) + (pa_l[2*kS + s1] + pa_l[3*kS + s1]);
      l0 += (m0 > 0.f ? 0.f : -1e30f);
      l1 += (m1 > 0.f ? 0.f : -1e30f);
      float es = __expf(l0) + __expf(l1);
      float mv; int mi;
      if (l1 > l0) { mv = l1; mi = s1; } else { mv = l0; mi = s0; }
#pragma unroll
      for (int off = 1; off < 64; off <<= 1) {
        float ov = __shfl_xor(mv, off);
        int oi = __shfl_xor(mi, off);
        if (ov > mv || (ov == mv && oi < mi)) { mv = ov; mi = oi; }
        es += __shfl_xor(es, off);
      }
      if (tid == 0) {
        out[b * kT + t] = (float)mi;
        out[kB * kT + b * kT + t] = mv - __logf(es);
      }
      if (mi == s0) m0 = 0.f;
      if (mi == s1) m1 = 0.f;
      ptr_cur = mi;
    }
    // no barrier needed before PH_A (writes pg_l only; pa_l rewritten in PH_C)
  }
}

}  // namespace

extern "C" void kernel_launch(void* const* d_in, const int* in_sizes, int n_in,
                              void* d_out, int out_size, void* d_ws, size_t ws_size,
                              hipStream_t stream) {
  const float* stat_g = (const float*)d_in[0];
  const float* dyn_g  = (const float*)d_in[1];
  const float* W_s   = (const float*)d_in[3];
  const float* b_s   = (const float*)d_in[4];
  const float* W_d   = (const float*)d_in[5];
  const float* b_d   = (const float*)d_in[6];
  const float* W_dec = (const float*)d_in[7];
  const float* b_dec = (const float*)d_in[8];
  const float* vv1   = (const float*)d_in[9];
  const float* ww1   = (const float*)d_in[10];
  const float* vv2   = (const float*)d_in[11];
  const float* ww2   = (const float*)d_in[12];
  const float* W_ih  = (const float*)d_in[13];
  const float* W_hh  = (const float*)d_in[14];
  const float* b_ih  = (const float*)d_in[15];
  const float* b_hh  = (const float*)d_in[16];

  float* ws = (float*)d_ws;
  float* out = (float*)d_out;

  prep_w<<<1, 256, 0, stream>>>(W_ih, W_dec, b_ih, b_dec, ww1, ww2, ws);
  prep_sh<<<kB, 256, 0, stream>>>(stat_g, dyn_g, W_s, b_s, W_d, b_d, ws);
  prep_base<<<dim3(kB, 2), 256, 0, stream>>>(ww1, ww2, ws);
  prep_m2<<<kB, 256, 0, stream>>>(ws);          // uses SHG scratch
  prep_gi<<<kB, 256, 0, stream>>>(stat_g, ws);  // overlays SHG/DHG after m2
  ptrnet_main<<<kB, 512, 0, stream>>>(dyn_g, vv1, vv2, b_hh, W_hh, ws, out);
}

// Round 21
// 970.570 us; speedup vs baseline: 2.1345x; 1.2151x over previous
//
#include <hip/hip_runtime.h>

// DRL4SSP pointer-network decoder, MI355X (gfx950).
// Main kernel identical to round-19 (steady 703us, VALU-bound, zero spill).
// Prep-side only: prep_w parallelized across 64 blocks (was 1); prep_m2
// merged into prep_base (grid 64x3). 64 blocks x 512 threads, 127 steps,
// 5 barriers/step.

namespace {

constexpr int kB = 64, kSS = 8, kDS = 4, kH = 128, kS = 128, kT = 127, kG3 = 384;

// workspace layout (float offsets)
constexpr size_t OFF_BASE1 = 0;
constexpr size_t OFF_BASE2 = OFF_BASE1 + (size_t)kB * kH * kS;
constexpr size_t OFF_W1HT  = OFF_BASE2 + (size_t)kB * kH * kS;   // [k][h]
constexpr size_t OFF_W2DT  = OFF_W1HT  + (size_t)kH * kH;        // [k][h]
constexpr size_t OFF_WCT   = OFF_W2DT  + (size_t)kH * kH;        // WcombT [8][384]
constexpr size_t OFF_BCOMB = OFF_WCT   + (size_t)kSS * kG3;
constexpr size_t OFF_SHG   = OFF_BCOMB + kG3;                    // prep scratch [b][k][s]
constexpr size_t OFF_DHG   = OFF_SHG   + (size_t)kB * kH * kS;   // prep scratch
constexpr size_t OFF_GIALL = OFF_SHG;                            // overlay: [b][129][384]
constexpr size_t OFF_M2    = OFF_GIALL + (size_t)kB * (kS + 1) * kG3;  // [b][s][h]

// static-LDS layout (float offsets)
constexpr int L_BASE1 = 0;        // 16384 (holds 2*base1)
constexpr int L_BASE2 = 16384;    // 16384 (holds 2*base2)
constexpr int L_BH    = 32768;    // 384
constexpr int L_PG    = 33152;    // 1536  [4 seg][3 gate][128]
constexpr int L_PU    = 34688;    // 512
constexpr int L_PA    = 35200;    // 512
constexpr int L_WSUM  = 35712;    // 4
constexpr int LDS_FLOATS = 35716; // 142,864 B

__device__ __forceinline__ float rlane(float v, int l) {
  return __uint_as_float(__builtin_amdgcn_readlane(__float_as_uint(v), (unsigned)l));
}

// ---------------- precompute kernels ----------------

// Parallelized: 64 blocks x 256 threads, grid-stride over all four arrays.
__global__ void prep_w(const float* __restrict__ W_ih, const float* __restrict__ W_dec,
                       const float* __restrict__ b_ih, const float* __restrict__ b_dec,
                       const float* __restrict__ ww1, const float* __restrict__ ww2,
                       float* __restrict__ ws) {
  const int gid = blockIdx.x * 256 + threadIdx.x;
  const int gstride = 64 * 256;
  float* WcT   = ws + OFF_WCT;
  float* bcomb = ws + OFF_BCOMB;
  float* w1hT  = ws + OFF_W1HT;
  float* w2dT  = ws + OFF_W2DT;
  for (int idx = gid; idx < kSS * kG3; idx += gstride) {
    int i = idx / kG3, j = idx % kG3;
    float acc = 0.f;
    for (int k = 0; k < kH; ++k) acc = fmaf(W_ih[j * kH + k], W_dec[k * kSS + i], acc);
    WcT[idx] = acc;
  }
  for (int j = gid; j < kG3; j += gstride) {
    float acc = b_ih[j];
    for (int k = 0; k < kH; ++k) acc = fmaf(W_ih[j * kH + k], b_dec[k], acc);
    bcomb[j] = acc;
  }
  for (int idx = gid; idx < kH * kH; idx += gstride) {
    int k = idx >> 7, h = idx & 127;
    w1hT[idx] = ww1[h * kG3 + 2 * kH + k];
    w2dT[idx] = ww2[h * kG3 + kH + k];
  }
}

__global__ void prep_sh(const float* __restrict__ stat_g, const float* __restrict__ dyn_g,
                        const float* __restrict__ W_s, const float* __restrict__ b_s,
                        const float* __restrict__ W_d, const float* __restrict__ b_d,
                        float* __restrict__ ws) {
  const int b = blockIdx.x, tid = threadIdx.x;
  float* sh_g = ws + OFF_SHG;
  float* dh_g = ws + OFF_DHG;
  const float* sb = stat_g + (size_t)b * kSS * kS;
  const float* db = dyn_g + (size_t)b * kDS * kS;
  for (int idx = tid; idx < kH * kS; idx += 256) {
    int k = idx >> 7, s = idx & 127;
    float acc = b_s[k];
#pragma unroll
    for (int i = 0; i < kSS; ++i) acc = fmaf(W_s[k * kSS + i], sb[i * kS + s], acc);
    sh_g[(size_t)b * kH * kS + idx] = acc;
    float accd = b_d[k];
#pragma unroll
    for (int i = 0; i < kDS; ++i) accd = fmaf(W_d[k * kDS + i], db[i * kS + s], accd);
    dh_g[(size_t)b * kH * kS + idx] = accd;
  }
}

// which==0: base1; which==1: base2; which==2: M2[s][h] (merged prep_m2).
__global__ void prep_base(const float* __restrict__ ww1, const float* __restrict__ ww2,
                          float* __restrict__ ws) {
  const int b = blockIdx.x, which = blockIdx.y, tid = threadIdx.x;
  const float* sh_g = ws + OFF_SHG + (size_t)b * kH * kS;
  const float* dh_g = ws + OFF_DHG + (size_t)b * kH * kS;
  if (which == 2) {
    const float* w2dT = ws + OFF_W2DT;                        // [k][h]
    float* m2 = ws + OFF_M2 + (size_t)b * kS * kH;            // [s][h]
    for (int idx = tid; idx < kS * kH; idx += 256) {
      int s = idx >> 7, h = idx & 127;
      float acc = 0.f;
      for (int k = 0; k < kH; ++k)
        acc = fmaf(w2dT[k * kH + h], sh_g[k * kS + s], acc);
      m2[idx] = acc;
    }
    return;
  }
  const float* ww = which ? ww2 : ww1;
  const int dh_off = which ? 2 * kH : kH;
  float* dst = ws + (which ? OFF_BASE2 : OFF_BASE1) + (size_t)b * kH * kS;
  for (int idx = tid; idx < kH * kS / 4; idx += 256) {
    int h = idx >> 5, sq = idx & 31;
    const float* wrow = ww + h * kG3;
    float4 acc = make_float4(0.f, 0.f, 0.f, 0.f);
#pragma unroll 8
    for (int k = 0; k < kH; ++k) {
      float w = wrow[k];
      float4 v = *reinterpret_cast<const float4*>(sh_g + k * kS + sq * 4);
      acc.x = fmaf(w, v.x, acc.x); acc.y = fmaf(w, v.y, acc.y);
      acc.z = fmaf(w, v.z, acc.z); acc.w = fmaf(w, v.w, acc.w);
    }
#pragma unroll 8
    for (int k = 0; k < kH; ++k) {
      float w = wrow[dh_off + k];
      float4 v = *reinterpret_cast<const float4*>(dh_g + k * kS + sq * 4);
      acc.x = fmaf(w, v.x, acc.x); acc.y = fmaf(w, v.y, acc.y);
      acc.z = fmaf(w, v.z, acc.z); acc.w = fmaf(w, v.w, acc.w);
    }
    *reinterpret_cast<float4*>(dst + h * kS + sq * 4) = acc;
  }
}

// gi_all[b][s][j]; slot s=128 is the dec_in=0 case. Overlays SHG/DHG scratch.
__global__ void prep_gi(const float* __restrict__ stat_g, float* __restrict__ ws) {
  const int b = blockIdx.x, tid = threadIdx.x;
  const float* WcT = ws + OFF_WCT;
  const float* bcomb = ws + OFF_BCOMB;
  float* gia = ws + OFF_GIALL + (size_t)b * (kS + 1) * kG3;
  const float* sb = stat_g + (size_t)b * kSS * kS;
  for (int idx = tid; idx < (kS + 1) * kG3; idx += 256) {
    int s = idx / kG3, j = idx % kG3;
    float acc = bcomb[j];
#pragma unroll
    for (int i = 0; i < kSS; ++i) {
      float d = (s < kS) ? sb[i * kS + s] : 0.f;
      acc = fmaf(WcT[i * kG3 + j], d, acc);
    }
    gia[idx] = acc;
  }
}

// ---------------- main sequential kernel (identical to round 19) ----------------

__global__ __launch_bounds__(512, 2) void ptrnet_main(
    const float* __restrict__ dyn_g,
    const float* __restrict__ vv1_g, const float* __restrict__ vv2_g,
    const float* __restrict__ bhh_g, const float* __restrict__ Whh_g,
    const float* __restrict__ ws, float* __restrict__ out) {
  __shared__ float sm[LDS_FLOATS];
  const int b = blockIdx.x;
  const int tid = threadIdx.x;
  const int hh = tid & 127;
  const int seg = tid >> 7;            // 0..3
  const int lane = tid & 63;
  const int li = seg * 32 + (hh & 31);

  float* base1_l = sm + L_BASE1;   // 2*base1
  float* base2_l = sm + L_BASE2;   // 2*base2
  float* bh_l    = sm + L_BH;
  float* pg_l    = sm + L_PG;
  float* pu_l    = sm + L_PU;
  float* pa_l    = sm + L_PA;
  float* wsum_l  = sm + L_WSUM;

  // ---- LDS init (one-time): copy bases scaled by 2 ----
  {
    const float4* b1g = reinterpret_cast<const float4*>(ws + OFF_BASE1 + (size_t)b * kH * kS);
    const float4* b2g = reinterpret_cast<const float4*>(ws + OFF_BASE2 + (size_t)b * kH * kS);
    float4* b1l = reinterpret_cast<float4*>(base1_l);
    float4* b2l = reinterpret_cast<float4*>(base2_l);
    for (int i = tid; i < kH * kS / 4; i += 512) {
      float4 v1 = b1g[i], v2 = b2g[i];
      v1.x += v1.x; v1.y += v1.y; v1.z += v1.z; v1.w += v1.w;
      v2.x += v2.x; v2.y += v2.y; v2.z += v2.z; v2.w += v2.w;
      b1l[i] = v1; b2l[i] = v2;
    }
    if (tid < kG3) bh_l[tid] = bhh_g[tid];
  }

  // registerized mask bits for this thread's two s-values (same in all waves)
  float m0 = (lane == 0 || dyn_g[(size_t)b * kDS * kS + lane] != 0.f) ? 0.f : 1.f;
  float m1 = (dyn_g[(size_t)b * kDS * kS + lane + 64] != 0.f) ? 0.f : 1.f;
  int ptr_cur = kS;                    // slot 128 == dec_in = 0 (step 0)

  const float v_vv1 = vv1_g[li], v_vv2 = vv2_g[li];
  // per-seg vv sums (step-invariant)
  float vvsum1 = 0.f, vvsum2 = 0.f;
#pragma unroll
  for (int kk = 0; kk < 32; ++kk) {
    vvsum1 += rlane(v_vv1, kk);
    vvsum2 += rlane(v_vv2, kk);
  }
  float h_prev = 0.f;

  // stream bases
  const float* whp0 = Whh_g + (size_t)(0 * kH + hh) * kH + seg * 32;  // gate r
  const float* whp1 = whp0 + (size_t)kH * kH;                         // gate z
  const float* whp2 = whp1 + (size_t)kH * kH;                         // gate n
  const float* w1p = ws + OFF_W1HT + (size_t)(seg * 32) * kH + hh;
  const float* m2p = ws + OFF_M2 + (size_t)b * kS * kH + (size_t)(seg * 32) * kH + hh;
  const float* gia = ws + OFF_GIALL + (size_t)b * (kS + 1) * kG3;
  __syncthreads();

  for (int t = 0; t < kT; ++t) {
    // ---- PH_A: gi loads (consumed in PH_B) + gh partials (Whh streamed) ----
    float gi0, gi1, gi2;
    {
      const float* gp = gia + (size_t)ptr_cur * kG3 + li;
      gi0 = gp[0]; gi1 = gp[kH]; gi2 = gp[2 * kH];
      float4 q0[8], q1[8];
#pragma unroll
      for (int j = 0; j < 8; ++j) q0[j] = *reinterpret_cast<const float4*>(whp0 + 4 * j);
#pragma unroll
      for (int j = 0; j < 8; ++j) q1[j] = *reinterpret_cast<const float4*>(whp1 + 4 * j);
      float a0 = 0.f, a1 = 0.f;
#pragma unroll
      for (int j = 0; j < 8; ++j) {
        float4 w0 = q0[j], w1 = q1[j];
        float h0 = rlane(h_prev, 4 * j + 0), h1 = rlane(h_prev, 4 * j + 1);
        float h2 = rlane(h_prev, 4 * j + 2), h3 = rlane(h_prev, 4 * j + 3);
        a0 = fmaf(h0, w0.x, a0); a1 = fmaf(h0, w1.x, a1);
        a0 = fmaf(h1, w0.y, a0); a1 = fmaf(h1, w1.y, a1);
        a0 = fmaf(h2, w0.z, a0); a1 = fmaf(h2, w1.z, a1);
        a0 = fmaf(h3, w0.w, a0); a1 = fmaf(h3, w1.w, a1);
      }
#pragma unroll
      for (int j = 0; j < 8; ++j) q0[j] = *reinterpret_cast<const float4*>(whp2 + 4 * j);
      float a2x = 0.f, a2y = 0.f;
#pragma unroll
      for (int j = 0; j < 8; ++j) {
        float4 w = q0[j];
        a2x = fmaf(rlane(h_prev, 4 * j + 0), w.x, a2x);
        a2y = fmaf(rlane(h_prev, 4 * j + 1), w.y, a2y);
        a2x = fmaf(rlane(h_prev, 4 * j + 2), w.z, a2x);
        a2y = fmaf(rlane(h_prev, 4 * j + 3), w.w, a2y);
      }
      pg_l[(seg * 3 + 0) * kS + hh] = a0;
      pg_l[(seg * 3 + 1) * kS + hh] = a1;
      pg_l[(seg * 3 + 2) * kS + hh] = a2x + a2y;
    }
    __syncthreads();

    // ---- PH_B: GRU (replicated per-thread) + u1 partials (w1 streamed) ----
    {
      float b0[8], b1[8], b2[8], b3[8];
#pragma unroll
      for (int j = 0; j < 8; ++j) b0[j] = w1p[j * kH];
#pragma unroll
      for (int j = 0; j < 8; ++j) b1[j] = w1p[(8 + j) * kH];
#pragma unroll
      for (int j = 0; j < 8; ++j) b2[j] = w1p[(16 + j) * kH];
#pragma unroll
      for (int j = 0; j < 8; ++j) b3[j] = w1p[(24 + j) * kH];
      float gh0 = bh_l[li] +
          ((pg_l[(0*3+0)*kS+li] + pg_l[(1*3+0)*kS+li]) + (pg_l[(2*3+0)*kS+li] + pg_l[(3*3+0)*kS+li]));
      float gh1 = bh_l[kH + li] +
          ((pg_l[(0*3+1)*kS+li] + pg_l[(1*3+1)*kS+li]) + (pg_l[(2*3+1)*kS+li] + pg_l[(3*3+1)*kS+li]));
      float gh2 = bh_l[2*kH + li] +
          ((pg_l[(0*3+2)*kS+li] + pg_l[(1*3+2)*kS+li]) + (pg_l[(2*3+2)*kS+li] + pg_l[(3*3+2)*kS+li]));
      float r = 1.f / (1.f + __expf(-(gi0 + gh0)));
      float z = 1.f / (1.f + __expf(-(gi1 + gh1)));
      float x = gi2 + r * gh2;
      x = fminf(15.f, fmaxf(-15.f, x));
      float e = __expf(-2.f * x);
      float n = (1.f - e) / (1.f + e);
      float hnew = (1.f - z) * n + z * h_prev;
      h_prev = hnew;
      float acc0 = 0.f, acc1 = 0.f;
#pragma unroll
      for (int j = 0; j < 8; ++j) {
        acc0 = fmaf(rlane(hnew, j), b0[j], acc0);
        acc1 = fmaf(rlane(hnew, 8 + j), b1[j], acc1);
      }
#pragma unroll
      for (int j = 0; j < 8; ++j) {
        acc0 = fmaf(rlane(hnew, 16 + j), b2[j], acc0);
        acc1 = fmaf(rlane(hnew, 24 + j), b3[j], acc1);
      }
      pu_l[seg * kS + hh] = acc0 + acc1;
    }
    __syncthreads();

    // ---- PH_C: attn1 partials via vv - 2vv/(e^{2x}+1)  (2*base1 in LDS) ----
    {
      float v_u1 = (pu_l[li] + pu_l[kS + li]) + (pu_l[2*kS + li] + pu_l[3*kS + li]);
      float u2x = v_u1 + v_u1;
      float acc0 = 0.f, acc1 = 0.f;
#pragma unroll
      for (int kk = 0; kk < 16; ++kk) {
        float xa = base1_l[(seg * 32 + 2*kk) * kS + hh] + rlane(u2x, 2*kk);
        float xb = base1_l[(seg * 32 + 2*kk+1) * kS + hh] + rlane(u2x, 2*kk+1);
        float ra = __builtin_amdgcn_rcpf(__expf(xa) + 1.f);
        float rb = __builtin_amdgcn_rcpf(__expf(xb) + 1.f);
        acc0 = fmaf(rlane(v_vv1, 2*kk), ra, acc0);
        acc1 = fmaf(rlane(v_vv1, 2*kk+1), rb, acc1);
      }
      pa_l[seg * kS + hh] = vvsum1 - 2.f * (acc0 + acc1);
    }
    __syncthreads();

    // ---- PH_E: softmax1 exp + chunk sums + u2raw partials (M2 streamed) ----
    {
      float b0[8], b1[8], b2[8], b3[8];
#pragma unroll
      for (int j = 0; j < 8; ++j) b0[j] = m2p[j * kH];
#pragma unroll
      for (int j = 0; j < 8; ++j) b1[j] = m2p[(8 + j) * kH];
#pragma unroll
      for (int j = 0; j < 8; ++j) b2[j] = m2p[(16 + j) * kH];
#pragma unroll
      for (int j = 0; j < 8; ++j) b3[j] = m2p[(24 + j) * kH];
      float a = (pa_l[li] + pa_l[kS + li]) + (pa_l[2*kS + li] + pa_l[3*kS + li]);
      float ee = __expf(fminf(a, 60.f));
      float ssum = ee;
#pragma unroll
      for (int off = 1; off < 32; off <<= 1) ssum += __shfl_xor(ssum, off);
      if ((lane & 31) == 0) wsum_l[seg] = ssum;
      float acc0 = 0.f, acc1 = 0.f;
#pragma unroll
      for (int j = 0; j < 8; ++j) {
        acc0 = fmaf(rlane(ee, j), b0[j], acc0);
        acc1 = fmaf(rlane(ee, 8 + j), b1[j], acc1);
      }
#pragma unroll
      for (int j = 0; j < 8; ++j) {
        acc0 = fmaf(rlane(ee, 16 + j), b2[j], acc0);
        acc1 = fmaf(rlane(ee, 24 + j), b3[j], acc1);
      }
      pu_l[seg * kS + hh] = acc0 + acc1;   // u2raw partials
    }
    __syncthreads();

    // ---- PH_G: attn2 partials via vv - 2vv/(e^{2x}+1)  (2*base2 in LDS) ----
    {
      float rin2 = 2.0f / ((wsum_l[0] + wsum_l[1]) + (wsum_l[2] + wsum_l[3]));
      float v_u2x = ((pu_l[li] + pu_l[kS + li]) + (pu_l[2*kS + li] + pu_l[3*kS + li])) * rin2;
      float acc0 = 0.f, acc1 = 0.f;
#pragma unroll
      for (int kk = 0; kk < 16; ++kk) {
        float xa = base2_l[(seg * 32 + 2*kk) * kS + hh] + rlane(v_u2x, 2*kk);
        float xb = base2_l[(seg * 32 + 2*kk+1) * kS + hh] + rlane(v_u2x, 2*kk+1);
        float ra = __builtin_amdgcn_rcpf(__expf(xa) + 1.f);
        float rb = __builtin_amdgcn_rcpf(__expf(xb) + 1.f);
        acc0 = fmaf(rlane(v_vv2, 2*kk), ra, acc0);
        acc1 = fmaf(rlane(v_vv2, 2*kk+1), rb, acc1);
      }
      pa_l[seg * kS + hh] = vvsum2 - 2.f * (acc0 + acc1);
    }
    __syncthreads();

    // ---- PH_H: logits + argmax (all waves redundantly, register mask) ----
    {
      int s0 = lane, s1 = lane + 64;
      float l0 = (pa_l[s0] + pa_l[kS + s0]) + (pa_l[2*kS + s0] + pa_l[3*kS + s0]);
      float l1 = (pa_l[s1] + pa_l[kS + s1]) + (pa_l[2*kS + s1] + pa_l[3*kS + s1]);
      l0 += (m0 > 0.f ? 0.f : -1e30f);
      l1 += (m1 > 0.f ? 0.f : -1e30f);
      float es = __expf(l0) + __expf(l1);
      float mv; int mi;
      if (l1 > l0) { mv = l1; mi = s1; } else { mv = l0; mi = s0; }
#pragma unroll
      for (int off = 1; off < 64; off <<= 1) {
        float ov = __shfl_xor(mv, off);
        int oi = __shfl_xor(mi, off);
        if (ov > mv || (ov == mv && oi < mi)) { mv = ov; mi = oi; }
        es += __shfl_xor(es, off);
      }
      if (tid == 0) {
        out[b * kT + t] = (float)mi;
        out[kB * kT + b * kT + t] = mv - __logf(es);
      }
      if (mi == s0) m0 = 0.f;
      if (mi == s1) m1 = 0.f;
      ptr_cur = mi;
    }
    // no barrier needed before PH_A (writes pg_l only; pa_l rewritten in PH_C)
  }
}

}  // namespace

extern "C" void kernel_launch(void* const* d_in, const int* in_sizes, int n_in,
                              void* d_out, int out_size, void* d_ws, size_t ws_size,
                              hipStream_t stream) {
  const float* stat_g = (const float*)d_in[0];
  const float* dyn_g  = (const float*)d_in[1];
  const float* W_s   = (const float*)d_in[3];
  const float* b_s   = (const float*)d_in[4];
  const float* W_d   = (const float*)d_in[5];
  const float* b_d   = (const float*)d_in[6];
  const float* W_dec = (const float*)d_in[7];
  const float* b_dec = (const float*)d_in[8];
  const float* vv1   = (const float*)d_in[9];
  const float* ww1   = (const float*)d_in[10];
  const float* vv2   = (const float*)d_in[11];
  const float* ww2   = (const float*)d_in[12];
  const float* W_ih  = (const float*)d_in[13];
  const float* W_hh  = (const float*)d_in[14];
  const float* b_ih  = (const float*)d_in[15];
  const float* b_hh  = (const float*)d_in[16];

  float* ws = (float*)d_ws;
  float* out = (float*)d_out;

  prep_w<<<64, 256, 0, stream>>>(W_ih, W_dec, b_ih, b_dec, ww1, ww2, ws);
  prep_sh<<<kB, 256, 0, stream>>>(stat_g, dyn_g, W_s, b_s, W_d, b_d, ws);
  prep_base<<<dim3(kB, 3), 256, 0, stream>>>(ww1, ww2, ws);   // y==2 -> M2
  prep_gi<<<kB, 256, 0, stream>>>(stat_g, ws);                // overlays SHG/DHG
  ptrnet_main<<<kB, 512, 0, stream>>>(dyn_g, vv1, vv2, b_hh, W_hh, ws, out);
}